// Round 6
// baseline (3481.691 us; speedup 1.0000x reference)
//
#include <hip/hip_runtime.h>
#include <hip/hip_fp16.h>
#include <cstdint>
#include <cstddef>

#define NN 50000
#define NE 800000
#define HID 64
#define INF_ 128
#define BN_EPS 1e-5f
#define NGRP16 (NN / 16)     // 3125 node-16-groups (NN % 16 == 0)
#define SCAN_B 196           // ceil(50000/256)
#define PG 1568              // prop/appnp grid: 2 x 784 blocks (multiple of 8)

typedef unsigned long long u64;

// ---------------- fp16 pack/unpack ----------------
// float2 carrier = 4 halves; float4 carrier = 8 halves
__device__ __forceinline__ float4 h8_to_f4(float2 raw) {
    union { float f; __half2 h; } ua, ub;
    ua.f = raw.x; ub.f = raw.y;
    float2 fa = __half22float2(ua.h), fb = __half22float2(ub.h);
    return make_float4(fa.x, fa.y, fb.x, fb.y);
}
__device__ __forceinline__ float2 f4_to_h8(float4 v) {
    union { float f; __half2 h; } ua, ub;
    ua.h = __float22half2_rn(make_float2(v.x, v.y));
    ub.h = __float22half2_rn(make_float2(v.z, v.w));
    return make_float2(ua.f, ub.f);
}
struct f8 { float v[8]; };
__device__ __forceinline__ f8 h16_to_f8(float4 raw) {
    f8 r;
    union { float f; __half2 h; } u;
    float2 a;
    u.f = raw.x; a = __half22float2(u.h); r.v[0] = a.x; r.v[1] = a.y;
    u.f = raw.y; a = __half22float2(u.h); r.v[2] = a.x; r.v[3] = a.y;
    u.f = raw.z; a = __half22float2(u.h); r.v[4] = a.x; r.v[5] = a.y;
    u.f = raw.w; a = __half22float2(u.h); r.v[6] = a.x; r.v[7] = a.y;
    return r;
}
__device__ __forceinline__ float4 f8_to_h16(const f8& s) {
    union { float f; __half2 h; } u;
    float4 o;
    u.h = __float22half2_rn(make_float2(s.v[0], s.v[1])); o.x = u.f;
    u.h = __float22half2_rn(make_float2(s.v[2], s.v[3])); o.y = u.f;
    u.h = __float22half2_rn(make_float2(s.v[4], s.v[5])); o.z = u.f;
    u.h = __float22half2_rn(make_float2(s.v[6], s.v[7])); o.w = u.f;
    return o;
}

// read the physical XCD id (HW_REG_XCC_ID = 20, size 4) [verified gfx950]
__device__ __forceinline__ int xcd_id() {
    return __builtin_amdgcn_s_getreg((3 << 11) | 20) & 7;
}

// ---------------- graph prep ----------------

__global__ void count_k(const int* __restrict__ dst, int* __restrict__ cnt) {
    int e = blockIdx.x * blockDim.x + threadIdx.x;
    if (e < NE) atomicAdd(&cnt[dst[e]], 1);
}

__global__ void dinv_k(const int* __restrict__ cnt, float* __restrict__ dinv) {
    int n = blockIdx.x * blockDim.x + threadIdx.x;
    if (n < NN) dinv[n] = rsqrtf((float)(cnt[n] + 1));   // +1 self-loop
}

// parallel scan of PADDED degrees ((deg+3)&~3) -> offs; 3 kernels
__global__ void scan1_k(const int* __restrict__ cnt, int* __restrict__ offs,
                        int* __restrict__ bsum) {
    __shared__ int sh[256];
    int t = threadIdx.x, i = blockIdx.x * 256 + t;
    int v = (i < NN) ? ((cnt[i] + 3) & ~3) : 0;
    sh[t] = v;
    __syncthreads();
    for (int d = 1; d < 256; d <<= 1) {
        int u = (t >= d) ? sh[t - d] : 0;
        __syncthreads();
        sh[t] += u;
        __syncthreads();
    }
    if (i < NN) offs[i] = sh[t] - v;
    if (t == 255) bsum[blockIdx.x] = sh[255];
}

__global__ void scan2_k(const int* __restrict__ bsum, int* __restrict__ bpre,
                        int* __restrict__ offs) {
    __shared__ int sh[256];
    int t = threadIdx.x;
    int v = (t < SCAN_B) ? bsum[t] : 0;
    sh[t] = v;
    __syncthreads();
    for (int d = 1; d < 256; d <<= 1) {
        int u = (t >= d) ? sh[t - d] : 0;
        __syncthreads();
        sh[t] += u;
        __syncthreads();
    }
    bpre[t] = sh[t] - v;
    if (t == 255) offs[NN] = sh[255];
}

__global__ void scan3_k(int* __restrict__ offs, const int* __restrict__ bpre) {
    int i = blockIdx.x * blockDim.x + threadIdx.x;
    if (i < NN) offs[i] += bpre[i >> 8];
}

__global__ void pad_k(const int* __restrict__ cnt, const int* __restrict__ offs,
                      int2* __restrict__ edge2) {
    int n = blockIdx.x * blockDim.x + threadIdx.x;
    if (n >= NN) return;
    int e = offs[n] + cnt[n], e1 = offs[n + 1];
    for (; e < e1; ++e) edge2[e] = make_int2(0, 0);   // w = 0.0f
}

__global__ void scatter_k(const int* __restrict__ src, const int* __restrict__ dst,
                          const int* __restrict__ offs, int* __restrict__ cursor,
                          const float* __restrict__ dinv,
                          int2* __restrict__ edge2) {
    int e = blockIdx.x * blockDim.x + threadIdx.x;
    if (e < NE) {
        int s = src[e], d = dst[e];
        int pos = offs[d] + atomicAdd(&cursor[d], 1);
        edge2[pos] = make_int2(s, __float_as_int(dinv[s] * dinv[d]));
    }
}

// ---------------- dense matmul: Y[N,64] = X[N,K] @ W[K,64], split fp16 out --
template <int K, bool HIN>
__global__ __launch_bounds__(256) void mm_k(const void* __restrict__ Xa,
                                            const void* __restrict__ Xb,
                                            const float* __restrict__ W,
                                            float2* __restrict__ YA,
                                            float2* __restrict__ YB) {
    const int t = threadIdx.x;
    const int n0 = blockIdx.x * 64;
    const int r0 = (t >> 4) << 2;
    const int c0 = (t & 15) << 2;

    int r[4];
#pragma unroll
    for (int j = 0; j < 4; ++j) {
        int rr = n0 + r0 + j;
        r[j] = rr < NN ? rr : NN - 1;
    }
    const float4* Xr4[4];
    const float2* XrA[4];
    const float2* XrB[4];
#pragma unroll
    for (int j = 0; j < 4; ++j) {
        if (HIN) {
            XrA[j] = (const float2*)Xa + (size_t)r[j] * 8;
            XrB[j] = (const float2*)Xb + (size_t)r[j] * 8;
        } else {
            Xr4[j] = (const float4*)Xa + (size_t)r[j] * (K / 4);
        }
    }

    float acc[4][4];
#pragma unroll
    for (int j = 0; j < 4; ++j)
#pragma unroll
        for (int c = 0; c < 4; ++c) acc[j][c] = 0.f;

#pragma unroll 4
    for (int kq = 0; kq < K / 4; ++kq) {
        float4 xv[4];
#pragma unroll
        for (int j = 0; j < 4; ++j) {
            if (HIN)
                xv[j] = h8_to_f4(kq < 8 ? XrA[j][kq] : XrB[j][kq - 8]);
            else
                xv[j] = Xr4[j][kq];
        }
        float4 wv[4];
#pragma unroll
        for (int i = 0; i < 4; ++i)
            wv[i] = *(const float4*)(W + (size_t)(kq * 4 + i) * 64 + c0);
#pragma unroll
        for (int j = 0; j < 4; ++j) {
            acc[j][0] = fmaf(xv[j].x, wv[0].x, acc[j][0]);
            acc[j][1] = fmaf(xv[j].x, wv[0].y, acc[j][1]);
            acc[j][2] = fmaf(xv[j].x, wv[0].z, acc[j][2]);
            acc[j][3] = fmaf(xv[j].x, wv[0].w, acc[j][3]);
            acc[j][0] = fmaf(xv[j].y, wv[1].x, acc[j][0]);
            acc[j][1] = fmaf(xv[j].y, wv[1].y, acc[j][1]);
            acc[j][2] = fmaf(xv[j].y, wv[1].z, acc[j][2]);
            acc[j][3] = fmaf(xv[j].y, wv[1].w, acc[j][3]);
            acc[j][0] = fmaf(xv[j].z, wv[2].x, acc[j][0]);
            acc[j][1] = fmaf(xv[j].z, wv[2].y, acc[j][1]);
            acc[j][2] = fmaf(xv[j].z, wv[2].z, acc[j][2]);
            acc[j][3] = fmaf(xv[j].z, wv[2].w, acc[j][3]);
            acc[j][0] = fmaf(xv[j].w, wv[3].x, acc[j][0]);
            acc[j][1] = fmaf(xv[j].w, wv[3].y, acc[j][1]);
            acc[j][2] = fmaf(xv[j].w, wv[3].z, acc[j][2]);
            acc[j][3] = fmaf(xv[j].w, wv[3].w, acc[j][3]);
        }
    }

    const int half = c0 >> 5;
    const int co = (c0 & 31) >> 2;
    float2* Yh = half ? YB : YA;
#pragma unroll
    for (int j = 0; j < 4; ++j) {
        int rr = n0 + r0 + j;
        if (rr < NN)
            Yh[(size_t)rr * 8 + co] =
                f4_to_h8(make_float4(acc[j][0], acc[j][1], acc[j][2], acc[j][3]));
    }
}

// ---------------- propagate core: 16 nodes/wave over a 64B half-row --------
// lane = slot*4 + fl; slot in [0,16), fl in [0,4) -> feats [fl*8, fl*8+8) of the half
__device__ __forceinline__ void gather16(const float4* __restrict__ Xh,
                                         const u64* __restrict__ E8,
                                         int e0, int e1, int fl, float acc[8]) {
    for (int e = e0; e < e1; e += 4) {   // padded: e1-e0 multiple of 4
        u64 p0 = __builtin_nontemporal_load(E8 + e);
        u64 p1 = __builtin_nontemporal_load(E8 + e + 1);
        u64 p2 = __builtin_nontemporal_load(E8 + e + 2);
        u64 p3 = __builtin_nontemporal_load(E8 + e + 3);
        int s0 = (int)(p0 & 0xffffffffu), s1i = (int)(p1 & 0xffffffffu);
        int s2i = (int)(p2 & 0xffffffffu), s3 = (int)(p3 & 0xffffffffu);
        float w0 = __int_as_float((int)(p0 >> 32));
        float w1 = __int_as_float((int)(p1 >> 32));
        float w2 = __int_as_float((int)(p2 >> 32));
        float w3 = __int_as_float((int)(p3 >> 32));
        float4 r0 = Xh[(size_t)s0 * 4 + fl];
        float4 r1 = Xh[(size_t)s1i * 4 + fl];
        float4 r2 = Xh[(size_t)s2i * 4 + fl];
        float4 r3 = Xh[(size_t)s3 * 4 + fl];
        f8 x0 = h16_to_f8(r0), x1 = h16_to_f8(r1);
        f8 x2 = h16_to_f8(r2), x3 = h16_to_f8(r3);
#pragma unroll
        for (int j = 0; j < 8; ++j) {
            acc[j] = fmaf(w0, x0.v[j], acc[j]);
            acc[j] = fmaf(w1, x1.v[j], acc[j]);
            acc[j] = fmaf(w2, x2.v[j], acc[j]);
            acc[j] = fmaf(w3, x3.v[j], acc[j]);
        }
    }
}

__device__ __forceinline__ void prop_group(const float4* __restrict__ Xh,
                                           const int* __restrict__ offs,
                                           const u64* __restrict__ E8,
                                           const float* __restrict__ dinv,
                                           const float* __restrict__ biasH,
                                           float4* __restrict__ Yh,
                                           int g, int slot, int fl,
                                           float s1[8], float s2[8]) {
    int n = g * 16 + slot;
    float dn = dinv[n], dd = dn * dn;
    f8 self = h16_to_f8(Xh[(size_t)n * 4 + fl]);
    float acc[8];
#pragma unroll
    for (int j = 0; j < 8; ++j) acc[j] = dd * self.v[j];
    gather16(Xh, E8, offs[n], offs[n + 1], fl, acc);
    float4 b0 = ((const float4*)biasH)[fl * 2];
    float4 b1 = ((const float4*)biasH)[fl * 2 + 1];
    float b8[8] = { b0.x, b0.y, b0.z, b0.w, b1.x, b1.y, b1.z, b1.w };
    f8 o;
#pragma unroll
    for (int j = 0; j < 8; ++j) {
        acc[j] += b8[j];
        o.v[j] = acc[j];
        s1[j] += acc[j];
        s2[j] = fmaf(acc[j], acc[j], s2[j]);
    }
    Yh[(size_t)n * 4 + fl] = f8_to_h16(o);
}

__device__ __forceinline__ void red_slots(float s1[8], float s2[8]) {
#pragma unroll
    for (int m = 4; m <= 32; m <<= 1)
#pragma unroll
        for (int j = 0; j < 8; ++j) {
            s1[j] += __shfl_xor(s1[j], m, 64);
            s2[j] += __shfl_xor(s2[j], m, 64);
        }
}

// ---------------- propagate + bias + BN-stats, XCD-steered halves ----------
__global__ __launch_bounds__(256) void prop_stats_k(
        const float4* __restrict__ XA, const float4* __restrict__ XB,
        const int* __restrict__ offs, const u64* __restrict__ E8,
        const float* __restrict__ dinv, const float* __restrict__ bias,
        float4* __restrict__ YA, float4* __restrict__ YB,
        float* __restrict__ stats, int* __restrict__ q) {
    const int lane = threadIdx.x & 63;
    const int wave = threadIdx.x >> 6;
    const int slot = lane >> 2, fl = lane & 3;
    const int half = (xcd_id() >= 4) ? 1 : 0;

    float s1[8], s2[8];
#pragma unroll
    for (int j = 0; j < 8; ++j) { s1[j] = 0.f; s2[j] = 0.f; }

    {   // own half: accumulate stats in registers
        const float4* Xh = half ? XB : XA;
        float4* Yh = half ? YB : YA;
        const float* biasH = bias + half * 32;
        while (true) {
            int gg = 0;
            if (lane == 0) gg = atomicAdd(&q[half], 1);
            gg = __shfl(gg, 0, 64);
            if (gg >= NGRP16) break;
            prop_group(Xh, offs, E8, dinv, biasH, Yh, gg, slot, fl, s1, s2);
        }
    }

    red_slots(s1, s2);
    __shared__ float red[4][4][16];
    if (lane < 4) {
#pragma unroll
        for (int j = 0; j < 8; ++j) {
            red[wave][lane][j] = s1[j];
            red[wave][lane][8 + j] = s2[j];
        }
    }
    __syncthreads();
    int t = threadIdx.x;
    if (t < 64) {
        int j = t & 31, isq = t >> 5;
        int fi = j >> 3, c = (j & 7) + isq * 8;
        float a = red[0][fi][c] + red[1][fi][c] + red[2][fi][c] + red[3][fi][c];
        atomicAdd(&stats[isq * 64 + half * 32 + j], a);
    }

    {   // steal from the other half (rare; flush stats directly)
        const int oh = 1 - half;
        const float4* Xo = oh ? XB : XA;
        float4* Yo = oh ? YB : YA;
        const float* biasO = bias + oh * 32;
        float t1[8], t2[8];
#pragma unroll
        for (int j = 0; j < 8; ++j) { t1[j] = 0.f; t2[j] = 0.f; }
        bool any = false;
        while (true) {
            int gg = 0;
            if (lane == 0) gg = atomicAdd(&q[oh], 1);
            gg = __shfl(gg, 0, 64);
            if (gg >= NGRP16) break;
            prop_group(Xo, offs, E8, dinv, biasO, Yo, gg, slot, fl, t1, t2);
            any = true;
        }
        if (any) {
            red_slots(t1, t2);
            if (lane < 4) {
                int f0 = oh * 32 + lane * 8;
#pragma unroll
                for (int j = 0; j < 8; ++j) {
                    atomicAdd(&stats[f0 + j], t1[j]);
                    atomicAdd(&stats[64 + f0 + j], t2[j]);
                }
            }
        }
    }
}

// ---------------- batchnorm + relu: split fp16 in -> split fp16 out --------
__global__ void bn_relu_k(const float4* __restrict__ YA, const float4* __restrict__ YB,
                          const float* __restrict__ stats,
                          const float* __restrict__ g, const float* __restrict__ be,
                          float4* __restrict__ HA, float4* __restrict__ HB) {
    int i = blockIdx.x * blockDim.x + threadIdx.x;
    if (i >= NN * 8) return;
    int half = (i >= NN * 4) ? 1 : 0;
    int idx = i - half * NN * 4;
    int fl = idx & 3;
    int f0 = half * 32 + fl * 8;
    const float invN = 1.f / (float)NN;
    float4 sm0 = *(const float4*)(stats + f0);
    float4 sm1 = *(const float4*)(stats + f0 + 4);
    float4 sq0 = *(const float4*)(stats + 64 + f0);
    float4 sq1 = *(const float4*)(stats + 64 + f0 + 4);
    float4 gv0 = *(const float4*)(g + f0);
    float4 gv1 = *(const float4*)(g + f0 + 4);
    float4 bv0 = *(const float4*)(be + f0);
    float4 bv1 = *(const float4*)(be + f0 + 4);
    float sm[8] = { sm0.x, sm0.y, sm0.z, sm0.w, sm1.x, sm1.y, sm1.z, sm1.w };
    float sq[8] = { sq0.x, sq0.y, sq0.z, sq0.w, sq1.x, sq1.y, sq1.z, sq1.w };
    float gv[8] = { gv0.x, gv0.y, gv0.z, gv0.w, gv1.x, gv1.y, gv1.z, gv1.w };
    float bv[8] = { bv0.x, bv0.y, bv0.z, bv0.w, bv1.x, bv1.y, bv1.z, bv1.w };
    f8 y = h16_to_f8((half ? YB : YA)[idx]);
    f8 o;
#pragma unroll
    for (int j = 0; j < 8; ++j) {
        float m = sm[j] * invN;
        float v = sq[j] * invN - m * m;
        float val = fmaf(gv[j] * rsqrtf(v + BN_EPS), y.v[j] - m, bv[j]);
        o.v[j] = val > 0.f ? val : 0.f;
    }
    (half ? HB : HA)[idx] = f8_to_h16(o);
}

// ---------------- APPNP iteration, XCD-steered halves ----------------
__device__ __forceinline__ void appnp_group(const float4* __restrict__ Xh,
                                            const float4* __restrict__ H0h,
                                            const int* __restrict__ offs,
                                            const u64* __restrict__ E8,
                                            const float* __restrict__ dinv,
                                            float4* __restrict__ Yh,
                                            int g, int slot, int fl) {
    int n = g * 16 + slot;
    float dn = dinv[n], dd = dn * dn;
    f8 self = h16_to_f8(Xh[(size_t)n * 4 + fl]);
    float acc[8];
#pragma unroll
    for (int j = 0; j < 8; ++j) acc[j] = dd * self.v[j];
    gather16(Xh, E8, offs[n], offs[n + 1], fl, acc);
    f8 h0 = h16_to_f8(H0h[(size_t)n * 4 + fl]);
    f8 o;
#pragma unroll
    for (int j = 0; j < 8; ++j)
        o.v[j] = fmaf(0.9f, acc[j], 0.1f * h0.v[j]);
    Yh[(size_t)n * 4 + fl] = f8_to_h16(o);
}

__global__ __launch_bounds__(256) void appnp_k(
        const float4* __restrict__ XA, const float4* __restrict__ XB,
        const float4* __restrict__ H0A, const float4* __restrict__ H0B,
        const int* __restrict__ offs, const u64* __restrict__ E8,
        const float* __restrict__ dinv,
        float4* __restrict__ YA, float4* __restrict__ YB,
        int* __restrict__ q) {
    const int lane = threadIdx.x & 63;
    const int slot = lane >> 2, fl = lane & 3;
    const int half = (xcd_id() >= 4) ? 1 : 0;
#pragma unroll
    for (int ph = 0; ph < 2; ++ph) {
        int h = ph ? (1 - half) : half;
        const float4* Xh = h ? XB : XA;
        const float4* H0h = h ? H0B : H0A;
        float4* Yh = h ? YB : YA;
        while (true) {
            int gg = 0;
            if (lane == 0) gg = atomicAdd(&q[h], 1);
            gg = __shfl(gg, 0, 64);
            if (gg >= NGRP16) break;
            appnp_group(Xh, H0h, offs, E8, dinv, Yh, gg, slot, fl);
        }
    }
}

// ---------------- FC + log_softmax (split fp16 in, fp32 out) ----------------
__global__ __launch_bounds__(256) void final_k(const float2* __restrict__ HA,
                                               const float2* __restrict__ HB,
                                               const float* __restrict__ Wfc,
                                               const float* __restrict__ bfc,
                                               float* __restrict__ out) {
    const int t = threadIdx.x;
    const int n0 = blockIdx.x * 64;
    const int r0 = (t >> 4) << 2;
    const int c0 = (t & 15) << 2;

    int r[4];
#pragma unroll
    for (int j = 0; j < 4; ++j) {
        int rr = n0 + r0 + j;
        r[j] = rr < NN ? rr : NN - 1;
    }
    const float2* XrA[4];
    const float2* XrB[4];
#pragma unroll
    for (int j = 0; j < 4; ++j) {
        XrA[j] = HA + (size_t)r[j] * 8;
        XrB[j] = HB + (size_t)r[j] * 8;
    }

    float4 bf = *(const float4*)(bfc + c0);
    float acc[4][4];
#pragma unroll
    for (int j = 0; j < 4; ++j) {
        acc[j][0] = bf.x; acc[j][1] = bf.y; acc[j][2] = bf.z; acc[j][3] = bf.w;
    }

#pragma unroll 4
    for (int kq = 0; kq < 16; ++kq) {
        float4 xv[4];
#pragma unroll
        for (int j = 0; j < 4; ++j)
            xv[j] = h8_to_f4(kq < 8 ? XrA[j][kq] : XrB[j][kq - 8]);
        float4 wv[4];
#pragma unroll
        for (int i = 0; i < 4; ++i)
            wv[i] = *(const float4*)(Wfc + (size_t)(kq * 4 + i) * 64 + c0);
#pragma unroll
        for (int j = 0; j < 4; ++j) {
            acc[j][0] = fmaf(xv[j].x, wv[0].x, acc[j][0]);
            acc[j][1] = fmaf(xv[j].x, wv[0].y, acc[j][1]);
            acc[j][2] = fmaf(xv[j].x, wv[0].z, acc[j][2]);
            acc[j][3] = fmaf(xv[j].x, wv[0].w, acc[j][3]);
            acc[j][0] = fmaf(xv[j].y, wv[1].x, acc[j][0]);
            acc[j][1] = fmaf(xv[j].y, wv[1].y, acc[j][1]);
            acc[j][2] = fmaf(xv[j].y, wv[1].z, acc[j][2]);
            acc[j][3] = fmaf(xv[j].y, wv[1].w, acc[j][3]);
            acc[j][0] = fmaf(xv[j].z, wv[2].x, acc[j][0]);
            acc[j][1] = fmaf(xv[j].z, wv[2].y, acc[j][1]);
            acc[j][2] = fmaf(xv[j].z, wv[2].z, acc[j][2]);
            acc[j][3] = fmaf(xv[j].z, wv[2].w, acc[j][3]);
            acc[j][0] = fmaf(xv[j].w, wv[3].x, acc[j][0]);
            acc[j][1] = fmaf(xv[j].w, wv[3].y, acc[j][1]);
            acc[j][2] = fmaf(xv[j].w, wv[3].z, acc[j][2]);
            acc[j][3] = fmaf(xv[j].w, wv[3].w, acc[j][3]);
        }
    }

#pragma unroll
    for (int j = 0; j < 4; ++j) {
        float m = fmaxf(fmaxf(acc[j][0], acc[j][1]), fmaxf(acc[j][2], acc[j][3]));
#pragma unroll
        for (int d = 1; d <= 8; d <<= 1) m = fmaxf(m, __shfl_xor(m, d, 64));
        float s = expf(acc[j][0] - m) + expf(acc[j][1] - m) +
                  expf(acc[j][2] - m) + expf(acc[j][3] - m);
#pragma unroll
        for (int d = 1; d <= 8; d <<= 1) s += __shfl_xor(s, d, 64);
        float lse = m + logf(s);
        int rr = n0 + r0 + j;
        if (rr < NN)
            *(float4*)(out + (size_t)rr * 64 + c0) =
                make_float4(acc[j][0] - lse, acc[j][1] - lse,
                            acc[j][2] - lse, acc[j][3] - lse);
    }
}

// ---------------- host launch ----------------

static inline char* alignup(char* p, size_t a) {
    return (char*)(((uintptr_t)p + a - 1) & ~(uintptr_t)(a - 1));
}

extern "C" void kernel_launch(void* const* d_in, const int* in_sizes, int n_in,
                              void* d_out, int out_size, void* d_ws, size_t ws_size,
                              hipStream_t stream) {
    const float* x   = (const float*)d_in[0];
    const int*   ei  = (const int*)d_in[1];
    const float* W1  = (const float*)d_in[2];
    const float* b1  = (const float*)d_in[3];
    const float* W2  = (const float*)d_in[4];
    const float* b2  = (const float*)d_in[5];
    const float* Wx  = (const float*)d_in[6];
    const float* bx  = (const float*)d_in[7];
    const float* g1  = (const float*)d_in[8];
    const float* be1 = (const float*)d_in[9];
    const float* g2  = (const float*)d_in[10];
    const float* be2 = (const float*)d_in[11];
    const float* g3  = (const float*)d_in[12];
    const float* be3 = (const float*)d_in[13];
    const float* Wfc = (const float*)d_in[14];
    const float* bfc = (const float*)d_in[15];
    float* out = (float*)d_out;

    const int* srcA = ei;
    const int* dstA = ei + NE;

    char* p = (char*)d_ws;
    int*   deg    = (int*)p;   p += NN * 4;
    int*   cursor = (int*)p;   p += NN * 4;
    float* stats  = (float*)p; p += 512 * 4;
    int*   qarr   = (int*)p;   p += 64 * 4;     // 14 launches x 2 counters
    size_t zbytes = (size_t)(p - (char*)d_ws);
    p = alignup(p, 512);
    int*   offs  = (int*)p;    p += (NN + 4) * 4;   p = alignup(p, 512);
    float* dinv  = (float*)p;  p += NN * 4;         p = alignup(p, 512);
    int*   bsum  = (int*)p;    p += 256 * 4;
    int*   bpre  = (int*)p;    p += 256 * 4;        p = alignup(p, 512);
    int2*  edge2 = (int2*)p;   p += ((size_t)NE + 3 * NN + 256) * 8; p = alignup(p, 512);
    // split fp16 half-buffers, each NN*32 halves = NN*64 bytes (3.2 MB)
    float4* tmpA = (float4*)p; p += (size_t)NN * 64; p = alignup(p, 512);
    float4* tmpB = (float4*)p; p += (size_t)NN * 64; p = alignup(p, 512);
    float4* hbA  = (float4*)p; p += (size_t)NN * 64; p = alignup(p, 512);
    float4* hbB  = (float4*)p; p += (size_t)NN * 64; p = alignup(p, 512);
    float4* apA  = (float4*)p; p += (size_t)NN * 64; p = alignup(p, 512);
    float4* apB  = (float4*)p; p += (size_t)NN * 64; p = alignup(p, 512);
    float4* pbA  = (float4*)p; p += (size_t)NN * 64; p = alignup(p, 512);
    float4* pbB  = (float4*)p; p += (size_t)NN * 64;

    hipMemsetAsync(d_ws, 0, zbytes, stream);

    count_k<<<(NE + 255) / 256, 256, 0, stream>>>(dstA, deg);
    dinv_k<<<(NN + 255) / 256, 256, 0, stream>>>(deg, dinv);
    scan1_k<<<SCAN_B, 256, 0, stream>>>(deg, offs, bsum);
    scan2_k<<<1, 256, 0, stream>>>(bsum, bpre, offs);
    scan3_k<<<(NN + 255) / 256, 256, 0, stream>>>(offs, bpre);
    pad_k<<<(NN + 255) / 256, 256, 0, stream>>>(deg, offs, edge2);
    scatter_k<<<(NE + 255) / 256, 256, 0, stream>>>(srcA, dstA, offs, cursor, dinv, edge2);

    const u64* E8 = (const u64*)edge2;
    const int MMG = (NN + 63) / 64;          // 782
    const int BNG = (NN * 8 + 255) / 256;    // 1563
    int qi = 0;

    mm_k<INF_, false><<<MMG, 256, 0, stream>>>(x, nullptr, W1, (float2*)tmpA, (float2*)tmpB);
    prop_stats_k<<<PG, 256, 0, stream>>>(tmpA, tmpB, offs, E8, dinv, b1, pbA, pbB,
                                         stats + 0 * 128, qarr + 2 * qi++);
    bn_relu_k<<<BNG, 256, 0, stream>>>(pbA, pbB, stats + 0 * 128, g1, be1, hbA, hbB);

    mm_k<HID, true><<<MMG, 256, 0, stream>>>(hbA, hbB, W2, (float2*)tmpA, (float2*)tmpB);
    prop_stats_k<<<PG, 256, 0, stream>>>(tmpA, tmpB, offs, E8, dinv, b2, pbA, pbB,
                                         stats + 1 * 128, qarr + 2 * qi++);
    bn_relu_k<<<BNG, 256, 0, stream>>>(pbA, pbB, stats + 1 * 128, g2, be2, hbA, hbB);

    for (int L = 0; L < 2; ++L) {
        mm_k<HID, true><<<MMG, 256, 0, stream>>>(hbA, hbB, Wx + (size_t)L * 64 * 64,
                                                 (float2*)tmpA, (float2*)tmpB);
        prop_stats_k<<<PG, 256, 0, stream>>>(tmpA, tmpB, offs, E8, dinv,
                                             bx + (size_t)L * 64, pbA, pbB,
                                             stats + (2 + L) * 128, qarr + 2 * qi++);
        bn_relu_k<<<BNG, 256, 0, stream>>>(pbA, pbB, stats + (2 + L) * 128, g3, be3, hbA, hbB);
    }

    // APPNP: h0 = hb; ping-pong (tmp, ap)
    const float4 *curA = hbA, *curB = hbB;
    float4* bufsA[2] = { tmpA, apA };
    float4* bufsB[2] = { tmpB, apB };
    for (int it = 0; it < 10; ++it) {
        float4* oA = bufsA[it & 1];
        float4* oB = bufsB[it & 1];
        appnp_k<<<PG, 256, 0, stream>>>(curA, curB, hbA, hbB, offs, E8, dinv,
                                        oA, oB, qarr + 2 * qi++);
        curA = oA; curB = oB;
    }

    final_k<<<MMG, 256, 0, stream>>>((const float2*)curA, (const float2*)curB,
                                     Wfc, bfc, out);
}

// Round 7
// 659.162 us; speedup vs baseline: 5.2820x; 5.2820x over previous
//
#include <hip/hip_runtime.h>
#include <hip/hip_fp16.h>
#include <cstdint>
#include <cstddef>

#define NN 50000
#define NE 800000
#define HID 64
#define INF_ 128
#define BN_EPS 1e-5f
#define NGRP (NN / 8)        // 6250 node-octets (NN % 8 == 0)
#define SCAN_B 196           // ceil(50000/256)

// ---------------- fp16 pack/unpack ----------------
// float2 carrier = 4 halves; float4 carrier = 8 halves
__device__ __forceinline__ float4 h8_to_f4(float2 raw) {
    union { float f; __half2 h; } ua, ub;
    ua.f = raw.x; ub.f = raw.y;
    float2 fa = __half22float2(ua.h), fb = __half22float2(ub.h);
    return make_float4(fa.x, fa.y, fb.x, fb.y);
}
__device__ __forceinline__ float2 f4_to_h8(float4 v) {
    union { float f; __half2 h; } ua, ub;
    ua.h = __float22half2_rn(make_float2(v.x, v.y));
    ub.h = __float22half2_rn(make_float2(v.z, v.w));
    return make_float2(ua.f, ub.f);
}
struct f8 { float v[8]; };
__device__ __forceinline__ f8 h16_to_f8(float4 raw) {
    f8 r;
    union { float f; __half2 h; } u;
    float2 a;
    u.f = raw.x; a = __half22float2(u.h); r.v[0] = a.x; r.v[1] = a.y;
    u.f = raw.y; a = __half22float2(u.h); r.v[2] = a.x; r.v[3] = a.y;
    u.f = raw.z; a = __half22float2(u.h); r.v[4] = a.x; r.v[5] = a.y;
    u.f = raw.w; a = __half22float2(u.h); r.v[6] = a.x; r.v[7] = a.y;
    return r;
}
__device__ __forceinline__ float4 f8_to_h16(const f8& s) {
    union { float f; __half2 h; } u;
    float4 o;
    u.h = __float22half2_rn(make_float2(s.v[0], s.v[1])); o.x = u.f;
    u.h = __float22half2_rn(make_float2(s.v[2], s.v[3])); o.y = u.f;
    u.h = __float22half2_rn(make_float2(s.v[4], s.v[5])); o.z = u.f;
    u.h = __float22half2_rn(make_float2(s.v[6], s.v[7])); o.w = u.f;
    return o;
}

// ---------------- graph prep ----------------

__global__ void count_k(const int* __restrict__ dst, int* __restrict__ cnt) {
    int e = blockIdx.x * blockDim.x + threadIdx.x;
    if (e < NE) atomicAdd(&cnt[dst[e]], 1);
}

__global__ void dinv_k(const int* __restrict__ cnt, float* __restrict__ dinv) {
    int n = blockIdx.x * blockDim.x + threadIdx.x;
    if (n < NN) dinv[n] = rsqrtf((float)(cnt[n] + 1));   // +1 self-loop
}

// parallel scan of PADDED degrees ((deg+7)&~7) -> offs; 3 kernels
__global__ void scan1_k(const int* __restrict__ cnt, int* __restrict__ offs,
                        int* __restrict__ bsum) {
    __shared__ int sh[256];
    int t = threadIdx.x, i = blockIdx.x * 256 + t;
    int v = (i < NN) ? ((cnt[i] + 7) & ~7) : 0;
    sh[t] = v;
    __syncthreads();
    for (int d = 1; d < 256; d <<= 1) {
        int u = (t >= d) ? sh[t - d] : 0;
        __syncthreads();
        sh[t] += u;
        __syncthreads();
    }
    if (i < NN) offs[i] = sh[t] - v;
    if (t == 255) bsum[blockIdx.x] = sh[255];
}

__global__ void scan2_k(const int* __restrict__ bsum, int* __restrict__ bpre,
                        int* __restrict__ offs) {
    __shared__ int sh[256];
    int t = threadIdx.x;
    int v = (t < SCAN_B) ? bsum[t] : 0;
    sh[t] = v;
    __syncthreads();
    for (int d = 1; d < 256; d <<= 1) {
        int u = (t >= d) ? sh[t - d] : 0;
        __syncthreads();
        sh[t] += u;
        __syncthreads();
    }
    bpre[t] = sh[t] - v;
    if (t == 255) offs[NN] = sh[255];
}

__global__ void scan3_k(int* __restrict__ offs, const int* __restrict__ bpre) {
    int i = blockIdx.x * blockDim.x + threadIdx.x;
    if (i < NN) offs[i] += bpre[i >> 8];
}

__global__ void pad_k(const int* __restrict__ cnt, const int* __restrict__ offs,
                      int2* __restrict__ edge2) {
    int n = blockIdx.x * blockDim.x + threadIdx.x;
    if (n >= NN) return;
    int e = offs[n] + cnt[n], e1 = offs[n + 1];
    for (; e < e1; ++e) edge2[e] = make_int2(0, 0);   // w = 0.0f -> row 0, hot line
}

__global__ void scatter_k(const int* __restrict__ src, const int* __restrict__ dst,
                          const int* __restrict__ offs, int* __restrict__ cursor,
                          const float* __restrict__ dinv,
                          int2* __restrict__ edge2) {
    int e = blockIdx.x * blockDim.x + threadIdx.x;
    if (e < NE) {
        int s = src[e], d = dst[e];
        int pos = offs[d] + atomicAdd(&cursor[d], 1);
        edge2[pos] = make_int2(s, __float_as_int(dinv[s] * dinv[d]));
    }
}

// ---------------- dense matmul: Y[N,64] = X[N,K] @ W[K,64], fp16 out --------
template <int K, bool HIN>
__global__ __launch_bounds__(256) void mm_k(const void* __restrict__ Xv,
                                            const float* __restrict__ W,
                                            float2* __restrict__ Y) {
    const int t = threadIdx.x;
    const int n0 = blockIdx.x * 64;
    const int r0 = (t >> 4) << 2;
    const int c0 = (t & 15) << 2;

    int r[4];
#pragma unroll
    for (int j = 0; j < 4; ++j) {
        int rr = n0 + r0 + j;
        r[j] = rr < NN ? rr : NN - 1;
    }
    const float4* Xr4[4];
    const float2* Xr2[4];
#pragma unroll
    for (int j = 0; j < 4; ++j) {
        if (HIN) Xr2[j] = (const float2*)Xv + (size_t)r[j] * (K / 4);
        else     Xr4[j] = (const float4*)Xv + (size_t)r[j] * (K / 4);
    }

    float acc[4][4];
#pragma unroll
    for (int j = 0; j < 4; ++j)
#pragma unroll
        for (int c = 0; c < 4; ++c) acc[j][c] = 0.f;

#pragma unroll 4
    for (int kq = 0; kq < K / 4; ++kq) {
        float4 xv[4];
#pragma unroll
        for (int j = 0; j < 4; ++j)
            xv[j] = HIN ? h8_to_f4(Xr2[j][kq]) : Xr4[j][kq];
        float4 wv[4];
#pragma unroll
        for (int i = 0; i < 4; ++i)
            wv[i] = *(const float4*)(W + (size_t)(kq * 4 + i) * 64 + c0);
#pragma unroll
        for (int j = 0; j < 4; ++j) {
            acc[j][0] = fmaf(xv[j].x, wv[0].x, acc[j][0]);
            acc[j][1] = fmaf(xv[j].x, wv[0].y, acc[j][1]);
            acc[j][2] = fmaf(xv[j].x, wv[0].z, acc[j][2]);
            acc[j][3] = fmaf(xv[j].x, wv[0].w, acc[j][3]);
            acc[j][0] = fmaf(xv[j].y, wv[1].x, acc[j][0]);
            acc[j][1] = fmaf(xv[j].y, wv[1].y, acc[j][1]);
            acc[j][2] = fmaf(xv[j].y, wv[1].z, acc[j][2]);
            acc[j][3] = fmaf(xv[j].y, wv[1].w, acc[j][3]);
            acc[j][0] = fmaf(xv[j].z, wv[2].x, acc[j][0]);
            acc[j][1] = fmaf(xv[j].z, wv[2].y, acc[j][1]);
            acc[j][2] = fmaf(xv[j].z, wv[2].z, acc[j][2]);
            acc[j][3] = fmaf(xv[j].z, wv[2].w, acc[j][3]);
            acc[j][0] = fmaf(xv[j].w, wv[3].x, acc[j][0]);
            acc[j][1] = fmaf(xv[j].w, wv[3].y, acc[j][1]);
            acc[j][2] = fmaf(xv[j].w, wv[3].z, acc[j][2]);
            acc[j][3] = fmaf(xv[j].w, wv[3].w, acc[j][3]);
        }
    }

#pragma unroll
    for (int j = 0; j < 4; ++j) {
        int rr = n0 + r0 + j;
        if (rr < NN)
            Y[(size_t)rr * 16 + (t & 15)] =
                f4_to_h8(make_float4(acc[j][0], acc[j][1], acc[j][2], acc[j][3]));
    }
}

// ---------------- propagate core: 8 nodes/wave, 8 gathers in flight --------
// lane = slot*8 + fl; slot in [0,8), fl in [0,8) covering feats [fl*8, fl*8+8)
__device__ __forceinline__ void prop_gather8(const float4* __restrict__ X4,
                                             const int2* __restrict__ E,
                                             int e0, int e1, int fl,
                                             float acc[8], float acc2[8]) {
    for (int e = e0; e < e1; e += 8) {   // padded: e1-e0 multiple of 8
        int2 d[8];
#pragma unroll
        for (int i = 0; i < 8; ++i) d[i] = E[e + i];
        float4 rr[8];
#pragma unroll
        for (int i = 0; i < 8; ++i)
            rr[i] = X4[(size_t)d[i].x * 8 + fl];
#pragma unroll
        for (int i = 0; i < 8; ++i) {
            float w = __int_as_float(d[i].y);
            f8 x = h16_to_f8(rr[i]);
            float* a = (i & 1) ? acc2 : acc;
#pragma unroll
            for (int j = 0; j < 8; ++j)
                a[j] = fmaf(w, x.v[j], a[j]);
        }
    }
}

// ---------------- propagate + bias + BN-stats (fp16 in, fp16 out) ----------
__global__ __launch_bounds__(256) void prop_stats_k(
        const float4* __restrict__ X4, const int* __restrict__ offs,
        const int2* __restrict__ edge2, const float* __restrict__ dinv,
        const float* __restrict__ bias, float4* __restrict__ Y4,
        float* __restrict__ stats) {
    const int lane = threadIdx.x & 63;
    const int wave = threadIdx.x >> 6;
    const int slot = lane >> 3;
    const int fl = lane & 7;
    const int wid = blockIdx.x * 4 + wave;
    const int nw = gridDim.x * 4;

    float bias8[8];
    {
        float4 b0 = ((const float4*)bias)[fl * 2];
        float4 b1 = ((const float4*)bias)[fl * 2 + 1];
        bias8[0] = b0.x; bias8[1] = b0.y; bias8[2] = b0.z; bias8[3] = b0.w;
        bias8[4] = b1.x; bias8[5] = b1.y; bias8[6] = b1.z; bias8[7] = b1.w;
    }

    float s1[8], s2[8];
#pragma unroll
    for (int j = 0; j < 8; ++j) { s1[j] = 0.f; s2[j] = 0.f; }

    for (int g = wid; g < NGRP; g += nw) {
        int n = g * 8 + slot;
        float dn = dinv[n];
        float dd = dn * dn;
        f8 self = h16_to_f8(X4[(size_t)n * 8 + fl]);
        float acc[8], acc2[8];
#pragma unroll
        for (int j = 0; j < 8; ++j) { acc[j] = dd * self.v[j]; acc2[j] = 0.f; }
        int e0 = offs[n], e1 = offs[n + 1];
        prop_gather8(X4, edge2, e0, e1, fl, acc, acc2);
        f8 o;
#pragma unroll
        for (int j = 0; j < 8; ++j) {
            float a = acc[j] + acc2[j] + bias8[j];
            o.v[j] = a;
            s1[j] += a;
            s2[j] = fmaf(a, a, s2[j]);
        }
        Y4[(size_t)n * 8 + fl] = f8_to_h16(o);
    }

    // reduce across the 8 slots (lanes differing in bits 3,4,5)
#pragma unroll
    for (int m = 8; m <= 32; m <<= 1) {
#pragma unroll
        for (int j = 0; j < 8; ++j) {
            s1[j] += __shfl_xor(s1[j], m, 64);
            s2[j] += __shfl_xor(s2[j], m, 64);
        }
    }

    __shared__ float red[4][8][16];
    if (lane < 8) {
#pragma unroll
        for (int j = 0; j < 8; ++j) {
            red[wave][lane][j] = s1[j];
            red[wave][lane][8 + j] = s2[j];
        }
    }
    __syncthreads();
    int t = threadIdx.x;
    if (t < 128) {
        int j = t & 63;            // feature index
        int isq = t >> 6;          // 0 = sum, 1 = sumsq
        int fli = j >> 3, c = (j & 7) + isq * 8;
        float a = red[0][fli][c] + red[1][fli][c] + red[2][fli][c] + red[3][fli][c];
        atomicAdd(&stats[isq * 64 + j], a);
    }
}

// ---------------- batchnorm + relu: fp16 in -> fp16 out ----------------
__global__ void bn_relu_k(const float4* __restrict__ Y4, const float* __restrict__ stats,
                          const float* __restrict__ g, const float* __restrict__ be,
                          float4* __restrict__ H4) {
    int i = blockIdx.x * blockDim.x + threadIdx.x;
    if (i >= NN * 8) return;
    int fg = i & 7;
    const float invN = 1.f / (float)NN;
    float4 sm0 = ((const float4*)stats)[fg * 2];
    float4 sm1 = ((const float4*)stats)[fg * 2 + 1];
    float4 sq0 = ((const float4*)(stats + 64))[fg * 2];
    float4 sq1 = ((const float4*)(stats + 64))[fg * 2 + 1];
    float4 gv0 = ((const float4*)g)[fg * 2];
    float4 gv1 = ((const float4*)g)[fg * 2 + 1];
    float4 bv0 = ((const float4*)be)[fg * 2];
    float4 bv1 = ((const float4*)be)[fg * 2 + 1];
    float sm[8] = { sm0.x, sm0.y, sm0.z, sm0.w, sm1.x, sm1.y, sm1.z, sm1.w };
    float sq[8] = { sq0.x, sq0.y, sq0.z, sq0.w, sq1.x, sq1.y, sq1.z, sq1.w };
    float gv[8] = { gv0.x, gv0.y, gv0.z, gv0.w, gv1.x, gv1.y, gv1.z, gv1.w };
    float bv[8] = { bv0.x, bv0.y, bv0.z, bv0.w, bv1.x, bv1.y, bv1.z, bv1.w };
    f8 y = h16_to_f8(Y4[i]);
    f8 o;
#pragma unroll
    for (int j = 0; j < 8; ++j) {
        float m = sm[j] * invN;
        float v = sq[j] * invN - m * m;
        float val = fmaf(gv[j] * rsqrtf(v + BN_EPS), y.v[j] - m, bv[j]);
        o.v[j] = val > 0.f ? val : 0.f;
    }
    H4[i] = f8_to_h16(o);
}

// ---------------- APPNP iteration (fp16, 8 nodes/wave) ----------------
__global__ __launch_bounds__(256) void appnp_k(
        const float4* __restrict__ X4, const float4* __restrict__ H04,
        const int* __restrict__ offs, const int2* __restrict__ edge2,
        const float* __restrict__ dinv, float4* __restrict__ Y4) {
    const int lane = threadIdx.x & 63;
    const int wave = threadIdx.x >> 6;
    const int slot = lane >> 3;
    const int fl = lane & 7;
    const int wid = blockIdx.x * 4 + wave;
    if (wid >= NGRP) return;
    int n = wid * 8 + slot;
    float dn = dinv[n];
    float dd = dn * dn;
    f8 self = h16_to_f8(X4[(size_t)n * 8 + fl]);
    float acc[8], acc2[8];
#pragma unroll
    for (int j = 0; j < 8; ++j) { acc[j] = dd * self.v[j]; acc2[j] = 0.f; }
    int e0 = offs[n], e1 = offs[n + 1];
    prop_gather8(X4, edge2, e0, e1, fl, acc, acc2);
    f8 h0 = h16_to_f8(H04[(size_t)n * 8 + fl]);
    f8 o;
#pragma unroll
    for (int j = 0; j < 8; ++j)
        o.v[j] = fmaf(0.9f, acc[j] + acc2[j], 0.1f * h0.v[j]);
    Y4[(size_t)n * 8 + fl] = f8_to_h16(o);
}

// ---------------- FC + log_softmax (fp16 in, fp32 out) ----------------
__global__ __launch_bounds__(256) void final_k(const float2* __restrict__ H2,
                                               const float* __restrict__ Wfc,
                                               const float* __restrict__ bfc,
                                               float* __restrict__ out) {
    const int t = threadIdx.x;
    const int n0 = blockIdx.x * 64;
    const int r0 = (t >> 4) << 2;
    const int c0 = (t & 15) << 2;

    int r[4];
#pragma unroll
    for (int j = 0; j < 4; ++j) {
        int rr = n0 + r0 + j;
        r[j] = rr < NN ? rr : NN - 1;
    }
    const float2* Xr[4];
#pragma unroll
    for (int j = 0; j < 4; ++j) Xr[j] = H2 + (size_t)r[j] * 16;

    float4 bf = *(const float4*)(bfc + c0);
    float acc[4][4];
#pragma unroll
    for (int j = 0; j < 4; ++j) {
        acc[j][0] = bf.x; acc[j][1] = bf.y; acc[j][2] = bf.z; acc[j][3] = bf.w;
    }

#pragma unroll 4
    for (int kq = 0; kq < 16; ++kq) {
        float4 xv[4];
#pragma unroll
        for (int j = 0; j < 4; ++j) xv[j] = h8_to_f4(Xr[j][kq]);
        float4 wv[4];
#pragma unroll
        for (int i = 0; i < 4; ++i)
            wv[i] = *(const float4*)(Wfc + (size_t)(kq * 4 + i) * 64 + c0);
#pragma unroll
        for (int j = 0; j < 4; ++j) {
            acc[j][0] = fmaf(xv[j].x, wv[0].x, acc[j][0]);
            acc[j][1] = fmaf(xv[j].x, wv[0].y, acc[j][1]);
            acc[j][2] = fmaf(xv[j].x, wv[0].z, acc[j][2]);
            acc[j][3] = fmaf(xv[j].x, wv[0].w, acc[j][3]);
            acc[j][0] = fmaf(xv[j].y, wv[1].x, acc[j][0]);
            acc[j][1] = fmaf(xv[j].y, wv[1].y, acc[j][1]);
            acc[j][2] = fmaf(xv[j].y, wv[1].z, acc[j][2]);
            acc[j][3] = fmaf(xv[j].y, wv[1].w, acc[j][3]);
            acc[j][0] = fmaf(xv[j].z, wv[2].x, acc[j][0]);
            acc[j][1] = fmaf(xv[j].z, wv[2].y, acc[j][1]);
            acc[j][2] = fmaf(xv[j].z, wv[2].z, acc[j][2]);
            acc[j][3] = fmaf(xv[j].z, wv[2].w, acc[j][3]);
            acc[j][0] = fmaf(xv[j].w, wv[3].x, acc[j][0]);
            acc[j][1] = fmaf(xv[j].w, wv[3].y, acc[j][1]);
            acc[j][2] = fmaf(xv[j].w, wv[3].z, acc[j][2]);
            acc[j][3] = fmaf(xv[j].w, wv[3].w, acc[j][3]);
        }
    }

#pragma unroll
    for (int j = 0; j < 4; ++j) {
        float m = fmaxf(fmaxf(acc[j][0], acc[j][1]), fmaxf(acc[j][2], acc[j][3]));
#pragma unroll
        for (int d = 1; d <= 8; d <<= 1) m = fmaxf(m, __shfl_xor(m, d, 64));
        float s = expf(acc[j][0] - m) + expf(acc[j][1] - m) +
                  expf(acc[j][2] - m) + expf(acc[j][3] - m);
#pragma unroll
        for (int d = 1; d <= 8; d <<= 1) s += __shfl_xor(s, d, 64);
        float lse = m + logf(s);
        int rr = n0 + r0 + j;
        if (rr < NN)
            *(float4*)(out + (size_t)rr * 64 + c0) =
                make_float4(acc[j][0] - lse, acc[j][1] - lse,
                            acc[j][2] - lse, acc[j][3] - lse);
    }
}

// ---------------- host launch ----------------

static inline char* alignup(char* p, size_t a) {
    return (char*)(((uintptr_t)p + a - 1) & ~(uintptr_t)(a - 1));
}

extern "C" void kernel_launch(void* const* d_in, const int* in_sizes, int n_in,
                              void* d_out, int out_size, void* d_ws, size_t ws_size,
                              hipStream_t stream) {
    const float* x   = (const float*)d_in[0];
    const int*   ei  = (const int*)d_in[1];
    const float* W1  = (const float*)d_in[2];
    const float* b1  = (const float*)d_in[3];
    const float* W2  = (const float*)d_in[4];
    const float* b2  = (const float*)d_in[5];
    const float* Wx  = (const float*)d_in[6];
    const float* bx  = (const float*)d_in[7];
    const float* g1  = (const float*)d_in[8];
    const float* be1 = (const float*)d_in[9];
    const float* g2  = (const float*)d_in[10];
    const float* be2 = (const float*)d_in[11];
    const float* g3  = (const float*)d_in[12];
    const float* be3 = (const float*)d_in[13];
    const float* Wfc = (const float*)d_in[14];
    const float* bfc = (const float*)d_in[15];
    float* out = (float*)d_out;

    const int* srcA = ei;
    const int* dstA = ei + NE;

    char* p = (char*)d_ws;
    int*   deg    = (int*)p;   p += NN * 4;
    int*   cursor = (int*)p;   p += NN * 4;
    float* stats  = (float*)p; p += 512 * 4;
    size_t zbytes = (size_t)(p - (char*)d_ws);
    p = alignup(p, 512);
    int*   offs  = (int*)p;    p += (NN + 4) * 4;   p = alignup(p, 512);
    float* dinv  = (float*)p;  p += NN * 4;         p = alignup(p, 512);
    int*   bsum  = (int*)p;    p += 256 * 4;
    int*   bpre  = (int*)p;    p += 256 * 4;        p = alignup(p, 512);
    int2*  edge2 = (int2*)p;   p += ((size_t)NE + 8 * NN + 256) * 8; p = alignup(p, 512);
    float4* tmpH = (float4*)p; p += (size_t)NN * 64 * 2; p = alignup(p, 512);
    float4* hbH  = (float4*)p; p += (size_t)NN * 64 * 2; p = alignup(p, 512);
    float4* apH  = (float4*)p; p += (size_t)NN * 64 * 2; p = alignup(p, 512);
    float4* pbH  = (float4*)p; p += (size_t)NN * 64 * 2;

    hipMemsetAsync(d_ws, 0, zbytes, stream);

    count_k<<<(NE + 255) / 256, 256, 0, stream>>>(dstA, deg);
    dinv_k<<<(NN + 255) / 256, 256, 0, stream>>>(deg, dinv);
    scan1_k<<<SCAN_B, 256, 0, stream>>>(deg, offs, bsum);
    scan2_k<<<1, 256, 0, stream>>>(bsum, bpre, offs);
    scan3_k<<<(NN + 255) / 256, 256, 0, stream>>>(offs, bpre);
    pad_k<<<(NN + 255) / 256, 256, 0, stream>>>(deg, offs, edge2);
    scatter_k<<<(NE + 255) / 256, 256, 0, stream>>>(srcA, dstA, offs, cursor, dinv, edge2);

    const int MMG = (NN + 63) / 64;          // 782
    const int PG  = (NGRP + 3) / 4;          // 1563: one octet per wave
    const int BNG = (NN * 8 + 255) / 256;    // 1563

    mm_k<INF_, false><<<MMG, 256, 0, stream>>>(x, W1, (float2*)tmpH);
    prop_stats_k<<<PG, 256, 0, stream>>>(tmpH, offs, edge2, dinv, b1, pbH, stats + 0 * 128);
    bn_relu_k<<<BNG, 256, 0, stream>>>(pbH, stats + 0 * 128, g1, be1, hbH);

    mm_k<HID, true><<<MMG, 256, 0, stream>>>(hbH, W2, (float2*)tmpH);
    prop_stats_k<<<PG, 256, 0, stream>>>(tmpH, offs, edge2, dinv, b2, pbH, stats + 1 * 128);
    bn_relu_k<<<BNG, 256, 0, stream>>>(pbH, stats + 1 * 128, g2, be2, hbH);

    for (int L = 0; L < 2; ++L) {
        mm_k<HID, true><<<MMG, 256, 0, stream>>>(hbH, Wx + (size_t)L * 64 * 64, (float2*)tmpH);
        prop_stats_k<<<PG, 256, 0, stream>>>(tmpH, offs, edge2, dinv, bx + (size_t)L * 64,
                                             pbH, stats + (2 + L) * 128);
        bn_relu_k<<<BNG, 256, 0, stream>>>(pbH, stats + (2 + L) * 128, g3, be3, hbH);
    }

    // APPNP: h0 = hbH; ping-pong tmpH/apH
    const float4* h0 = hbH;
    const float4* cur = hbH;
    float4* bufs[2] = { tmpH, apH };
    for (int it = 0; it < 10; ++it) {
        float4* o = bufs[it & 1];
        appnp_k<<<PG, 256, 0, stream>>>(cur, h0, offs, edge2, dinv, o);
        cur = o;
    }

    final_k<<<MMG, 256, 0, stream>>>((const float2*)cur, Wfc, bfc, out);
}

// Round 8
// 629.959 us; speedup vs baseline: 5.5269x; 1.0464x over previous
//
#include <hip/hip_runtime.h>
#include <hip/hip_fp16.h>
#include <cstdint>
#include <cstddef>

#define NN 50000
#define NE 800000
#define HID 64
#define INF_ 128
#define BN_EPS 1e-5f
#define NGRP (NN / 8)        // 6250 node-octets (NN % 8 == 0)
#define SCAN_B 196           // ceil(50000/256)

typedef float floatx2 __attribute__((ext_vector_type(2)));

// ---------------- fp16 pack/unpack ----------------
__device__ __forceinline__ float4 h8_to_f4(float2 raw) {
    union { float f; __half2 h; } ua, ub;
    ua.f = raw.x; ub.f = raw.y;
    float2 fa = __half22float2(ua.h), fb = __half22float2(ub.h);
    return make_float4(fa.x, fa.y, fb.x, fb.y);
}
__device__ __forceinline__ float2 f4_to_h8(float4 v) {
    union { float f; __half2 h; } ua, ub;
    ua.h = __float22half2_rn(make_float2(v.x, v.y));
    ub.h = __float22half2_rn(make_float2(v.z, v.w));
    return make_float2(ua.f, ub.f);
}
struct f8 { float v[8]; };
__device__ __forceinline__ f8 h16_to_f8(float4 raw) {
    f8 r;
    union { float f; __half2 h; } u;
    float2 a;
    u.f = raw.x; a = __half22float2(u.h); r.v[0] = a.x; r.v[1] = a.y;
    u.f = raw.y; a = __half22float2(u.h); r.v[2] = a.x; r.v[3] = a.y;
    u.f = raw.z; a = __half22float2(u.h); r.v[4] = a.x; r.v[5] = a.y;
    u.f = raw.w; a = __half22float2(u.h); r.v[6] = a.x; r.v[7] = a.y;
    return r;
}
__device__ __forceinline__ float4 f8_to_h16(const f8& s) {
    union { float f; __half2 h; } u;
    float4 o;
    u.h = __float22half2_rn(make_float2(s.v[0], s.v[1])); o.x = u.f;
    u.h = __float22half2_rn(make_float2(s.v[2], s.v[3])); o.y = u.f;
    u.h = __float22half2_rn(make_float2(s.v[4], s.v[5])); o.z = u.f;
    u.h = __float22half2_rn(make_float2(s.v[6], s.v[7])); o.w = u.f;
    return o;
}

// ---------------- fp8 e4m3 (OCP, gfx950 HW cvt) pack/unpack ----------------
__device__ __forceinline__ void fp8x8_to_f(uint2 r, float out[8]) {
    floatx2 a = __builtin_amdgcn_cvt_pk_f32_fp8((int)r.x, false);
    floatx2 b = __builtin_amdgcn_cvt_pk_f32_fp8((int)r.x, true);
    floatx2 c = __builtin_amdgcn_cvt_pk_f32_fp8((int)r.y, false);
    floatx2 d = __builtin_amdgcn_cvt_pk_f32_fp8((int)r.y, true);
    out[0] = a[0]; out[1] = a[1]; out[2] = b[0]; out[3] = b[1];
    out[4] = c[0]; out[5] = c[1]; out[6] = d[0]; out[7] = d[1];
}
__device__ __forceinline__ uint2 f_to_fp8x8(const float v[8]) {
    int w0 = __builtin_amdgcn_cvt_pk_fp8_f32(v[0], v[1], 0, false);
    w0 = __builtin_amdgcn_cvt_pk_fp8_f32(v[2], v[3], w0, true);
    int w1 = __builtin_amdgcn_cvt_pk_fp8_f32(v[4], v[5], 0, false);
    w1 = __builtin_amdgcn_cvt_pk_fp8_f32(v[6], v[7], w1, true);
    uint2 o; o.x = (unsigned)w0; o.y = (unsigned)w1;
    return o;
}

// ---------------- graph prep ----------------

__global__ void count_k(const int* __restrict__ dst, int* __restrict__ cnt) {
    int e = blockIdx.x * blockDim.x + threadIdx.x;
    if (e < NE) atomicAdd(&cnt[dst[e]], 1);
}

__global__ void dinv_k(const int* __restrict__ cnt, float* __restrict__ dinv) {
    int n = blockIdx.x * blockDim.x + threadIdx.x;
    if (n < NN) dinv[n] = rsqrtf((float)(cnt[n] + 1));   // +1 self-loop
}

// parallel scan of PADDED degrees ((deg+7)&~7) -> offs; 3 kernels
__global__ void scan1_k(const int* __restrict__ cnt, int* __restrict__ offs,
                        int* __restrict__ bsum) {
    __shared__ int sh[256];
    int t = threadIdx.x, i = blockIdx.x * 256 + t;
    int v = (i < NN) ? ((cnt[i] + 7) & ~7) : 0;
    sh[t] = v;
    __syncthreads();
    for (int d = 1; d < 256; d <<= 1) {
        int u = (t >= d) ? sh[t - d] : 0;
        __syncthreads();
        sh[t] += u;
        __syncthreads();
    }
    if (i < NN) offs[i] = sh[t] - v;
    if (t == 255) bsum[blockIdx.x] = sh[255];
}

__global__ void scan2_k(const int* __restrict__ bsum, int* __restrict__ bpre,
                        int* __restrict__ offs) {
    __shared__ int sh[256];
    int t = threadIdx.x;
    int v = (t < SCAN_B) ? bsum[t] : 0;
    sh[t] = v;
    __syncthreads();
    for (int d = 1; d < 256; d <<= 1) {
        int u = (t >= d) ? sh[t - d] : 0;
        __syncthreads();
        sh[t] += u;
        __syncthreads();
    }
    bpre[t] = sh[t] - v;
    if (t == 255) offs[NN] = sh[255];
}

__global__ void scan3_k(int* __restrict__ offs, const int* __restrict__ bpre) {
    int i = blockIdx.x * blockDim.x + threadIdx.x;
    if (i < NN) offs[i] += bpre[i >> 8];
}

__global__ void pad_k(const int* __restrict__ cnt, const int* __restrict__ offs,
                      int2* __restrict__ edge2) {
    int n = blockIdx.x * blockDim.x + threadIdx.x;
    if (n >= NN) return;
    int e = offs[n] + cnt[n], e1 = offs[n + 1];
    for (; e < e1; ++e) edge2[e] = make_int2(0, 0);   // w = 0.0f -> row 0, hot line
}

__global__ void scatter_k(const int* __restrict__ src, const int* __restrict__ dst,
                          const int* __restrict__ offs, int* __restrict__ cursor,
                          const float* __restrict__ dinv,
                          int2* __restrict__ edge2) {
    int e = blockIdx.x * blockDim.x + threadIdx.x;
    if (e < NE) {
        int s = src[e], d = dst[e];
        int pos = offs[d] + atomicAdd(&cursor[d], 1);
        edge2[pos] = make_int2(s, __float_as_int(dinv[s] * dinv[d]));
    }
}

// ---------------- dense matmul: Y[N,64] = X[N,K] @ W[K,64], fp16 out --------
template <int K, bool HIN>
__global__ __launch_bounds__(256) void mm_k(const void* __restrict__ Xv,
                                            const float* __restrict__ W,
                                            float2* __restrict__ Y) {
    const int t = threadIdx.x;
    const int n0 = blockIdx.x * 64;
    const int r0 = (t >> 4) << 2;
    const int c0 = (t & 15) << 2;

    int r[4];
#pragma unroll
    for (int j = 0; j < 4; ++j) {
        int rr = n0 + r0 + j;
        r[j] = rr < NN ? rr : NN - 1;
    }
    const float4* Xr4[4];
    const float2* Xr2[4];
#pragma unroll
    for (int j = 0; j < 4; ++j) {
        if (HIN) Xr2[j] = (const float2*)Xv + (size_t)r[j] * (K / 4);
        else     Xr4[j] = (const float4*)Xv + (size_t)r[j] * (K / 4);
    }

    float acc[4][4];
#pragma unroll
    for (int j = 0; j < 4; ++j)
#pragma unroll
        for (int c = 0; c < 4; ++c) acc[j][c] = 0.f;

#pragma unroll 4
    for (int kq = 0; kq < K / 4; ++kq) {
        float4 xv[4];
#pragma unroll
        for (int j = 0; j < 4; ++j)
            xv[j] = HIN ? h8_to_f4(Xr2[j][kq]) : Xr4[j][kq];
        float4 wv[4];
#pragma unroll
        for (int i = 0; i < 4; ++i)
            wv[i] = *(const float4*)(W + (size_t)(kq * 4 + i) * 64 + c0);
#pragma unroll
        for (int j = 0; j < 4; ++j) {
            acc[j][0] = fmaf(xv[j].x, wv[0].x, acc[j][0]);
            acc[j][1] = fmaf(xv[j].x, wv[0].y, acc[j][1]);
            acc[j][2] = fmaf(xv[j].x, wv[0].z, acc[j][2]);
            acc[j][3] = fmaf(xv[j].x, wv[0].w, acc[j][3]);
            acc[j][0] = fmaf(xv[j].y, wv[1].x, acc[j][0]);
            acc[j][1] = fmaf(xv[j].y, wv[1].y, acc[j][1]);
            acc[j][2] = fmaf(xv[j].y, wv[1].z, acc[j][2]);
            acc[j][3] = fmaf(xv[j].y, wv[1].w, acc[j][3]);
            acc[j][0] = fmaf(xv[j].z, wv[2].x, acc[j][0]);
            acc[j][1] = fmaf(xv[j].z, wv[2].y, acc[j][1]);
            acc[j][2] = fmaf(xv[j].z, wv[2].z, acc[j][2]);
            acc[j][3] = fmaf(xv[j].z, wv[2].w, acc[j][3]);
            acc[j][0] = fmaf(xv[j].w, wv[3].x, acc[j][0]);
            acc[j][1] = fmaf(xv[j].w, wv[3].y, acc[j][1]);
            acc[j][2] = fmaf(xv[j].w, wv[3].z, acc[j][2]);
            acc[j][3] = fmaf(xv[j].w, wv[3].w, acc[j][3]);
        }
    }

#pragma unroll
    for (int j = 0; j < 4; ++j) {
        int rr = n0 + r0 + j;
        if (rr < NN)
            Y[(size_t)rr * 16 + (t & 15)] =
                f4_to_h8(make_float4(acc[j][0], acc[j][1], acc[j][2], acc[j][3]));
    }
}

// ---------------- fp16 propagate core: 8 nodes/wave, 8 gathers in flight ----
__device__ __forceinline__ void prop_gather8(const float4* __restrict__ X4,
                                             const int2* __restrict__ E,
                                             int e0, int e1, int fl,
                                             float acc[8], float acc2[8]) {
    for (int e = e0; e < e1; e += 8) {   // padded: e1-e0 multiple of 8
        int2 d[8];
#pragma unroll
        for (int i = 0; i < 8; ++i) d[i] = E[e + i];
        float4 rr[8];
#pragma unroll
        for (int i = 0; i < 8; ++i)
            rr[i] = X4[(size_t)d[i].x * 8 + fl];
#pragma unroll
        for (int i = 0; i < 8; ++i) {
            float w = __int_as_float(d[i].y);
            f8 x = h16_to_f8(rr[i]);
            float* a = (i & 1) ? acc2 : acc;
#pragma unroll
            for (int j = 0; j < 8; ++j)
                a[j] = fmaf(w, x.v[j], a[j]);
        }
    }
}

// ---------------- propagate + bias + BN-stats (fp16 in, fp16 out) ----------
__global__ __launch_bounds__(256) void prop_stats_k(
        const float4* __restrict__ X4, const int* __restrict__ offs,
        const int2* __restrict__ edge2, const float* __restrict__ dinv,
        const float* __restrict__ bias, float4* __restrict__ Y4,
        float* __restrict__ stats) {
    const int lane = threadIdx.x & 63;
    const int wave = threadIdx.x >> 6;
    const int slot = lane >> 3;
    const int fl = lane & 7;
    const int wid = blockIdx.x * 4 + wave;
    const int nw = gridDim.x * 4;

    float bias8[8];
    {
        float4 b0 = ((const float4*)bias)[fl * 2];
        float4 b1 = ((const float4*)bias)[fl * 2 + 1];
        bias8[0] = b0.x; bias8[1] = b0.y; bias8[2] = b0.z; bias8[3] = b0.w;
        bias8[4] = b1.x; bias8[5] = b1.y; bias8[6] = b1.z; bias8[7] = b1.w;
    }

    float s1[8], s2[8];
#pragma unroll
    for (int j = 0; j < 8; ++j) { s1[j] = 0.f; s2[j] = 0.f; }

    for (int g = wid; g < NGRP; g += nw) {
        int n = g * 8 + slot;
        float dn = dinv[n];
        float dd = dn * dn;
        f8 self = h16_to_f8(X4[(size_t)n * 8 + fl]);
        float acc[8], acc2[8];
#pragma unroll
        for (int j = 0; j < 8; ++j) { acc[j] = dd * self.v[j]; acc2[j] = 0.f; }
        int e0 = offs[n], e1 = offs[n + 1];
        prop_gather8(X4, edge2, e0, e1, fl, acc, acc2);
        f8 o;
#pragma unroll
        for (int j = 0; j < 8; ++j) {
            float a = acc[j] + acc2[j] + bias8[j];
            o.v[j] = a;
            s1[j] += a;
            s2[j] = fmaf(a, a, s2[j]);
        }
        Y4[(size_t)n * 8 + fl] = f8_to_h16(o);
    }

    // reduce across the 8 slots (lanes differing in bits 3,4,5)
#pragma unroll
    for (int m = 8; m <= 32; m <<= 1) {
#pragma unroll
        for (int j = 0; j < 8; ++j) {
            s1[j] += __shfl_xor(s1[j], m, 64);
            s2[j] += __shfl_xor(s2[j], m, 64);
        }
    }

    __shared__ float red[4][8][16];
    if (lane < 8) {
#pragma unroll
        for (int j = 0; j < 8; ++j) {
            red[wave][lane][j] = s1[j];
            red[wave][lane][8 + j] = s2[j];
        }
    }
    __syncthreads();
    int t = threadIdx.x;
    if (t < 128) {
        int j = t & 63;            // feature index
        int isq = t >> 6;          // 0 = sum, 1 = sumsq
        int fli = j >> 3, c = (j & 7) + isq * 8;
        float a = red[0][fli][c] + red[1][fli][c] + red[2][fli][c] + red[3][fli][c];
        atomicAdd(&stats[isq * 64 + j], a);
    }
}

// ---------------- batchnorm + relu: fp16 in -> fp16 out ----------------
__global__ void bn_relu_k(const float4* __restrict__ Y4, const float* __restrict__ stats,
                          const float* __restrict__ g, const float* __restrict__ be,
                          float4* __restrict__ H4) {
    int i = blockIdx.x * blockDim.x + threadIdx.x;
    if (i >= NN * 8) return;
    int fg = i & 7;
    const float invN = 1.f / (float)NN;
    float4 sm0 = ((const float4*)stats)[fg * 2];
    float4 sm1 = ((const float4*)stats)[fg * 2 + 1];
    float4 sq0 = ((const float4*)(stats + 64))[fg * 2];
    float4 sq1 = ((const float4*)(stats + 64))[fg * 2 + 1];
    float4 gv0 = ((const float4*)g)[fg * 2];
    float4 gv1 = ((const float4*)g)[fg * 2 + 1];
    float4 bv0 = ((const float4*)be)[fg * 2];
    float4 bv1 = ((const float4*)be)[fg * 2 + 1];
    float sm[8] = { sm0.x, sm0.y, sm0.z, sm0.w, sm1.x, sm1.y, sm1.z, sm1.w };
    float sq[8] = { sq0.x, sq0.y, sq0.z, sq0.w, sq1.x, sq1.y, sq1.z, sq1.w };
    float gv[8] = { gv0.x, gv0.y, gv0.z, gv0.w, gv1.x, gv1.y, gv1.z, gv1.w };
    float bv[8] = { bv0.x, bv0.y, bv0.z, bv0.w, bv1.x, bv1.y, bv1.z, bv1.w };
    f8 y = h16_to_f8(Y4[i]);
    f8 o;
#pragma unroll
    for (int j = 0; j < 8; ++j) {
        float m = sm[j] * invN;
        float v = sq[j] * invN - m * m;
        float val = fmaf(gv[j] * rsqrtf(v + BN_EPS), y.v[j] - m, bv[j]);
        o.v[j] = val > 0.f ? val : 0.f;
    }
    H4[i] = f8_to_h16(o);
}

// ---------------- fp16 -> fp8 row conversion ----------------
__global__ void cvt16to8_k(const float4* __restrict__ H4, uint2* __restrict__ X8) {
    int i = blockIdx.x * blockDim.x + threadIdx.x;
    if (i >= NN * 8) return;
    f8 v = h16_to_f8(H4[i]);
    X8[i] = f_to_fp8x8(v.v);
}

// ---------------- fp8 propagate core ----------------
__device__ __forceinline__ void prop_gather8_f8(const uint2* __restrict__ X8,
                                                const int2* __restrict__ E,
                                                int e0, int e1, int fl,
                                                float acc[8], float acc2[8]) {
    for (int e = e0; e < e1; e += 8) {
        int2 d[8];
#pragma unroll
        for (int i = 0; i < 8; ++i) d[i] = E[e + i];
        uint2 rr[8];
#pragma unroll
        for (int i = 0; i < 8; ++i)
            rr[i] = X8[(size_t)d[i].x * 8 + fl];
#pragma unroll
        for (int i = 0; i < 8; ++i) {
            float w = __int_as_float(d[i].y);
            float x[8];
            fp8x8_to_f(rr[i], x);
            float* a = (i & 1) ? acc2 : acc;
#pragma unroll
            for (int j = 0; j < 8; ++j)
                a[j] = fmaf(w, x[j], a[j]);
        }
    }
}

// ---------------- APPNP iteration: fp8 gather, fp16 h0, fp8/fp16 out -------
template <bool OUT16>
__global__ __launch_bounds__(256) void appnp8_k(
        const uint2* __restrict__ X8, const float4* __restrict__ H04,
        const int* __restrict__ offs, const int2* __restrict__ edge2,
        const float* __restrict__ dinv,
        uint2* __restrict__ Y8, float4* __restrict__ Y16) {
    const int lane = threadIdx.x & 63;
    const int wave = threadIdx.x >> 6;
    const int slot = lane >> 3;
    const int fl = lane & 7;
    const int wid = blockIdx.x * 4 + wave;
    if (wid >= NGRP) return;
    int n = wid * 8 + slot;
    float dn = dinv[n];
    float dd = dn * dn;
    float self[8];
    fp8x8_to_f(X8[(size_t)n * 8 + fl], self);
    float acc[8], acc2[8];
#pragma unroll
    for (int j = 0; j < 8; ++j) { acc[j] = dd * self[j]; acc2[j] = 0.f; }
    int e0 = offs[n], e1 = offs[n + 1];
    prop_gather8_f8(X8, edge2, e0, e1, fl, acc, acc2);
    f8 h0 = h16_to_f8(H04[(size_t)n * 8 + fl]);
    f8 o;
#pragma unroll
    for (int j = 0; j < 8; ++j)
        o.v[j] = fmaf(0.9f, acc[j] + acc2[j], 0.1f * h0.v[j]);
    if (OUT16)
        Y16[(size_t)n * 8 + fl] = f8_to_h16(o);
    else
        Y8[(size_t)n * 8 + fl] = f_to_fp8x8(o.v);
}

// ---------------- FC + log_softmax (fp16 in, fp32 out) ----------------
__global__ __launch_bounds__(256) void final_k(const float2* __restrict__ H2,
                                               const float* __restrict__ Wfc,
                                               const float* __restrict__ bfc,
                                               float* __restrict__ out) {
    const int t = threadIdx.x;
    const int n0 = blockIdx.x * 64;
    const int r0 = (t >> 4) << 2;
    const int c0 = (t & 15) << 2;

    int r[4];
#pragma unroll
    for (int j = 0; j < 4; ++j) {
        int rr = n0 + r0 + j;
        r[j] = rr < NN ? rr : NN - 1;
    }
    const float2* Xr[4];
#pragma unroll
    for (int j = 0; j < 4; ++j) Xr[j] = H2 + (size_t)r[j] * 16;

    float4 bf = *(const float4*)(bfc + c0);
    float acc[4][4];
#pragma unroll
    for (int j = 0; j < 4; ++j) {
        acc[j][0] = bf.x; acc[j][1] = bf.y; acc[j][2] = bf.z; acc[j][3] = bf.w;
    }

#pragma unroll 4
    for (int kq = 0; kq < 16; ++kq) {
        float4 xv[4];
#pragma unroll
        for (int j = 0; j < 4; ++j) xv[j] = h8_to_f4(Xr[j][kq]);
        float4 wv[4];
#pragma unroll
        for (int i = 0; i < 4; ++i)
            wv[i] = *(const float4*)(Wfc + (size_t)(kq * 4 + i) * 64 + c0);
#pragma unroll
        for (int j = 0; j < 4; ++j) {
            acc[j][0] = fmaf(xv[j].x, wv[0].x, acc[j][0]);
            acc[j][1] = fmaf(xv[j].x, wv[0].y, acc[j][1]);
            acc[j][2] = fmaf(xv[j].x, wv[0].z, acc[j][2]);
            acc[j][3] = fmaf(xv[j].x, wv[0].w, acc[j][3]);
            acc[j][0] = fmaf(xv[j].y, wv[1].x, acc[j][0]);
            acc[j][1] = fmaf(xv[j].y, wv[1].y, acc[j][1]);
            acc[j][2] = fmaf(xv[j].y, wv[1].z, acc[j][2]);
            acc[j][3] = fmaf(xv[j].y, wv[1].w, acc[j][3]);
            acc[j][0] = fmaf(xv[j].z, wv[2].x, acc[j][0]);
            acc[j][1] = fmaf(xv[j].z, wv[2].y, acc[j][1]);
            acc[j][2] = fmaf(xv[j].z, wv[2].z, acc[j][2]);
            acc[j][3] = fmaf(xv[j].z, wv[2].w, acc[j][3]);
            acc[j][0] = fmaf(xv[j].w, wv[3].x, acc[j][0]);
            acc[j][1] = fmaf(xv[j].w, wv[3].y, acc[j][1]);
            acc[j][2] = fmaf(xv[j].w, wv[3].z, acc[j][2]);
            acc[j][3] = fmaf(xv[j].w, wv[3].w, acc[j][3]);
        }
    }

#pragma unroll
    for (int j = 0; j < 4; ++j) {
        float m = fmaxf(fmaxf(acc[j][0], acc[j][1]), fmaxf(acc[j][2], acc[j][3]));
#pragma unroll
        for (int d = 1; d <= 8; d <<= 1) m = fmaxf(m, __shfl_xor(m, d, 64));
        float s = expf(acc[j][0] - m) + expf(acc[j][1] - m) +
                  expf(acc[j][2] - m) + expf(acc[j][3] - m);
#pragma unroll
        for (int d = 1; d <= 8; d <<= 1) s += __shfl_xor(s, d, 64);
        float lse = m + logf(s);
        int rr = n0 + r0 + j;
        if (rr < NN)
            *(float4*)(out + (size_t)rr * 64 + c0) =
                make_float4(acc[j][0] - lse, acc[j][1] - lse,
                            acc[j][2] - lse, acc[j][3] - lse);
    }
}

// ---------------- host launch ----------------

static inline char* alignup(char* p, size_t a) {
    return (char*)(((uintptr_t)p + a - 1) & ~(uintptr_t)(a - 1));
}

extern "C" void kernel_launch(void* const* d_in, const int* in_sizes, int n_in,
                              void* d_out, int out_size, void* d_ws, size_t ws_size,
                              hipStream_t stream) {
    const float* x   = (const float*)d_in[0];
    const int*   ei  = (const int*)d_in[1];
    const float* W1  = (const float*)d_in[2];
    const float* b1  = (const float*)d_in[3];
    const float* W2  = (const float*)d_in[4];
    const float* b2  = (const float*)d_in[5];
    const float* Wx  = (const float*)d_in[6];
    const float* bx  = (const float*)d_in[7];
    const float* g1  = (const float*)d_in[8];
    const float* be1 = (const float*)d_in[9];
    const float* g2  = (const float*)d_in[10];
    const float* be2 = (const float*)d_in[11];
    const float* g3  = (const float*)d_in[12];
    const float* be3 = (const float*)d_in[13];
    const float* Wfc = (const float*)d_in[14];
    const float* bfc = (const float*)d_in[15];
    float* out = (float*)d_out;

    const int* srcA = ei;
    const int* dstA = ei + NE;

    char* p = (char*)d_ws;
    int*   deg    = (int*)p;   p += NN * 4;
    int*   cursor = (int*)p;   p += NN * 4;
    float* stats  = (float*)p; p += 512 * 4;
    size_t zbytes = (size_t)(p - (char*)d_ws);
    p = alignup(p, 512);
    int*   offs  = (int*)p;    p += (NN + 4) * 4;   p = alignup(p, 512);
    float* dinv  = (float*)p;  p += NN * 4;         p = alignup(p, 512);
    int*   bsum  = (int*)p;    p += 256 * 4;
    int*   bpre  = (int*)p;    p += 256 * 4;        p = alignup(p, 512);
    int2*  edge2 = (int2*)p;   p += ((size_t)NE + 8 * NN + 256) * 8; p = alignup(p, 512);
    float4* tmpH = (float4*)p; p += (size_t)NN * 64 * 2; p = alignup(p, 512);
    float4* hbH  = (float4*)p; p += (size_t)NN * 64 * 2; p = alignup(p, 512);
    float4* apH  = (float4*)p; p += (size_t)NN * 64 * 2; p = alignup(p, 512);
    float4* pbH  = (float4*)p; p += (size_t)NN * 64 * 2; p = alignup(p, 512);
    uint2*  x8a  = (uint2*)p;  p += (size_t)NN * 64;     p = alignup(p, 512);
    uint2*  x8b  = (uint2*)p;  p += (size_t)NN * 64;

    hipMemsetAsync(d_ws, 0, zbytes, stream);

    count_k<<<(NE + 255) / 256, 256, 0, stream>>>(dstA, deg);
    dinv_k<<<(NN + 255) / 256, 256, 0, stream>>>(deg, dinv);
    scan1_k<<<SCAN_B, 256, 0, stream>>>(deg, offs, bsum);
    scan2_k<<<1, 256, 0, stream>>>(bsum, bpre, offs);
    scan3_k<<<(NN + 255) / 256, 256, 0, stream>>>(offs, bpre);
    pad_k<<<(NN + 255) / 256, 256, 0, stream>>>(deg, offs, edge2);
    scatter_k<<<(NE + 255) / 256, 256, 0, stream>>>(srcA, dstA, offs, cursor, dinv, edge2);

    const int MMG = (NN + 63) / 64;          // 782
    const int PG  = (NGRP + 3) / 4;          // 1563: one octet per wave
    const int BNG = (NN * 8 + 255) / 256;    // 1563

    mm_k<INF_, false><<<MMG, 256, 0, stream>>>(x, W1, (float2*)tmpH);
    prop_stats_k<<<PG, 256, 0, stream>>>(tmpH, offs, edge2, dinv, b1, pbH, stats + 0 * 128);
    bn_relu_k<<<BNG, 256, 0, stream>>>(pbH, stats + 0 * 128, g1, be1, hbH);

    mm_k<HID, true><<<MMG, 256, 0, stream>>>(hbH, W2, (float2*)tmpH);
    prop_stats_k<<<PG, 256, 0, stream>>>(tmpH, offs, edge2, dinv, b2, pbH, stats + 1 * 128);
    bn_relu_k<<<BNG, 256, 0, stream>>>(pbH, stats + 1 * 128, g2, be2, hbH);

    for (int L = 0; L < 2; ++L) {
        mm_k<HID, true><<<MMG, 256, 0, stream>>>(hbH, Wx + (size_t)L * 64 * 64, (float2*)tmpH);
        prop_stats_k<<<PG, 256, 0, stream>>>(tmpH, offs, edge2, dinv, bx + (size_t)L * 64,
                                             pbH, stats + (2 + L) * 128);
        bn_relu_k<<<BNG, 256, 0, stream>>>(pbH, stats + (2 + L) * 128, g3, be3, hbH);
    }

    // APPNP in fp8: x8a <- fp8(hbH); 9 fp8->fp8 iters ping-pong; 10th -> fp16 apH
    cvt16to8_k<<<BNG, 256, 0, stream>>>(hbH, x8a);
    uint2* bufs8[2] = { x8b, x8a };          // iteration it writes bufs8[it&1^...]
    const uint2* cur8 = x8a;
    for (int it = 0; it < 9; ++it) {
        uint2* o8 = (cur8 == x8a) ? x8b : x8a;
        appnp8_k<false><<<PG, 256, 0, stream>>>(cur8, hbH, offs, edge2, dinv, o8, nullptr);
        cur8 = o8;
    }
    appnp8_k<true><<<PG, 256, 0, stream>>>(cur8, hbH, offs, edge2, dinv, nullptr, apH);

    final_k<<<MMG, 256, 0, stream>>>((const float2*)apH, Wfc, bfc, out);
}

// Round 9
// 624.897 us; speedup vs baseline: 5.5716x; 1.0081x over previous
//
#include <hip/hip_runtime.h>
#include <hip/hip_fp16.h>
#include <cstdint>
#include <cstddef>

#define NN 50000
#define NE 800000
#define HID 64
#define INF_ 128
#define BN_EPS 1e-5f
#define NGRP (NN / 8)        // 6250 node-octets for fp16 props
#define NG16 (NN / 16)       // 3125 node-16-groups for fp8 APPNP
#define SCAN_B 196           // ceil(50000/256)

typedef float floatx2 __attribute__((ext_vector_type(2)));

// ---------------- fp16 pack/unpack ----------------
__device__ __forceinline__ float4 h8_to_f4(float2 raw) {
    union { float f; __half2 h; } ua, ub;
    ua.f = raw.x; ub.f = raw.y;
    float2 fa = __half22float2(ua.h), fb = __half22float2(ub.h);
    return make_float4(fa.x, fa.y, fb.x, fb.y);
}
__device__ __forceinline__ float2 f4_to_h8(float4 v) {
    union { float f; __half2 h; } ua, ub;
    ua.h = __float22half2_rn(make_float2(v.x, v.y));
    ub.h = __float22half2_rn(make_float2(v.z, v.w));
    return make_float2(ua.f, ub.f);
}
struct f8 { float v[8]; };
__device__ __forceinline__ f8 h16_to_f8(float4 raw) {
    f8 r;
    union { float f; __half2 h; } u;
    float2 a;
    u.f = raw.x; a = __half22float2(u.h); r.v[0] = a.x; r.v[1] = a.y;
    u.f = raw.y; a = __half22float2(u.h); r.v[2] = a.x; r.v[3] = a.y;
    u.f = raw.z; a = __half22float2(u.h); r.v[4] = a.x; r.v[5] = a.y;
    u.f = raw.w; a = __half22float2(u.h); r.v[6] = a.x; r.v[7] = a.y;
    return r;
}
__device__ __forceinline__ float4 f8_to_h16(const f8& s) {
    union { float f; __half2 h; } u;
    float4 o;
    u.h = __float22half2_rn(make_float2(s.v[0], s.v[1])); o.x = u.f;
    u.h = __float22half2_rn(make_float2(s.v[2], s.v[3])); o.y = u.f;
    u.h = __float22half2_rn(make_float2(s.v[4], s.v[5])); o.z = u.f;
    u.h = __float22half2_rn(make_float2(s.v[6], s.v[7])); o.w = u.f;
    return o;
}

// ---------------- fp8 e4m3 (OCP, gfx950 HW cvt) pack/unpack ----------------
__device__ __forceinline__ void fp8x8_to_f(unsigned lo, unsigned hi, float out[8]) {
    floatx2 a = __builtin_amdgcn_cvt_pk_f32_fp8((int)lo, false);
    floatx2 b = __builtin_amdgcn_cvt_pk_f32_fp8((int)lo, true);
    floatx2 c = __builtin_amdgcn_cvt_pk_f32_fp8((int)hi, false);
    floatx2 d = __builtin_amdgcn_cvt_pk_f32_fp8((int)hi, true);
    out[0] = a[0]; out[1] = a[1]; out[2] = b[0]; out[3] = b[1];
    out[4] = c[0]; out[5] = c[1]; out[6] = d[0]; out[7] = d[1];
}
__device__ __forceinline__ void fp8x16_to_f(uint4 r, float out[16]) {
    fp8x8_to_f(r.x, r.y, out);
    fp8x8_to_f(r.z, r.w, out + 8);
}
__device__ __forceinline__ uint2 f_to_fp8x8(const float v[8]) {
    int w0 = __builtin_amdgcn_cvt_pk_fp8_f32(v[0], v[1], 0, false);
    w0 = __builtin_amdgcn_cvt_pk_fp8_f32(v[2], v[3], w0, true);
    int w1 = __builtin_amdgcn_cvt_pk_fp8_f32(v[4], v[5], 0, false);
    w1 = __builtin_amdgcn_cvt_pk_fp8_f32(v[6], v[7], w1, true);
    uint2 o; o.x = (unsigned)w0; o.y = (unsigned)w1;
    return o;
}
__device__ __forceinline__ uint4 f_to_fp8x16(const float v[16]) {
    uint2 a = f_to_fp8x8(v), b = f_to_fp8x8(v + 8);
    uint4 o; o.x = a.x; o.y = a.y; o.z = b.x; o.w = b.y;
    return o;
}

// ---------------- graph prep ----------------

__global__ void count_k(const int* __restrict__ dst, int* __restrict__ cnt) {
    int e = blockIdx.x * blockDim.x + threadIdx.x;
    if (e < NE) atomicAdd(&cnt[dst[e]], 1);
}

__global__ void dinv_k(const int* __restrict__ cnt, float* __restrict__ dinv) {
    int n = blockIdx.x * blockDim.x + threadIdx.x;
    if (n < NN) dinv[n] = rsqrtf((float)(cnt[n] + 1));   // +1 self-loop
}

// parallel scan of PADDED degrees ((deg+7)&~7) -> offs; 3 kernels
__global__ void scan1_k(const int* __restrict__ cnt, int* __restrict__ offs,
                        int* __restrict__ bsum) {
    __shared__ int sh[256];
    int t = threadIdx.x, i = blockIdx.x * 256 + t;
    int v = (i < NN) ? ((cnt[i] + 7) & ~7) : 0;
    sh[t] = v;
    __syncthreads();
    for (int d = 1; d < 256; d <<= 1) {
        int u = (t >= d) ? sh[t - d] : 0;
        __syncthreads();
        sh[t] += u;
        __syncthreads();
    }
    if (i < NN) offs[i] = sh[t] - v;
    if (t == 255) bsum[blockIdx.x] = sh[255];
}

__global__ void scan2_k(const int* __restrict__ bsum, int* __restrict__ bpre,
                        int* __restrict__ offs) {
    __shared__ int sh[256];
    int t = threadIdx.x;
    int v = (t < SCAN_B) ? bsum[t] : 0;
    sh[t] = v;
    __syncthreads();
    for (int d = 1; d < 256; d <<= 1) {
        int u = (t >= d) ? sh[t - d] : 0;
        __syncthreads();
        sh[t] += u;
        __syncthreads();
    }
    bpre[t] = sh[t] - v;
    if (t == 255) offs[NN] = sh[255];
}

__global__ void scan3_k(int* __restrict__ offs, const int* __restrict__ bpre) {
    int i = blockIdx.x * blockDim.x + threadIdx.x;
    if (i < NN) offs[i] += bpre[i >> 8];
}

__global__ void pad_k(const int* __restrict__ cnt, const int* __restrict__ offs,
                      int2* __restrict__ edge2) {
    int n = blockIdx.x * blockDim.x + threadIdx.x;
    if (n >= NN) return;
    int e = offs[n] + cnt[n], e1 = offs[n + 1];
    for (; e < e1; ++e) edge2[e] = make_int2(0, 0);   // w = 0.0f -> row 0, hot line
}

__global__ void scatter_k(const int* __restrict__ src, const int* __restrict__ dst,
                          const int* __restrict__ offs, int* __restrict__ cursor,
                          const float* __restrict__ dinv,
                          int2* __restrict__ edge2) {
    int e = blockIdx.x * blockDim.x + threadIdx.x;
    if (e < NE) {
        int s = src[e], d = dst[e];
        int pos = offs[d] + atomicAdd(&cursor[d], 1);
        edge2[pos] = make_int2(s, __float_as_int(dinv[s] * dinv[d]));
    }
}

// ---------------- dense matmul: Y[N,64] = X[N,K] @ W[K,64], fp16 out --------
template <int K, bool HIN>
__global__ __launch_bounds__(256) void mm_k(const void* __restrict__ Xv,
                                            const float* __restrict__ W,
                                            float2* __restrict__ Y) {
    const int t = threadIdx.x;
    const int n0 = blockIdx.x * 64;
    const int r0 = (t >> 4) << 2;
    const int c0 = (t & 15) << 2;

    int r[4];
#pragma unroll
    for (int j = 0; j < 4; ++j) {
        int rr = n0 + r0 + j;
        r[j] = rr < NN ? rr : NN - 1;
    }
    const float4* Xr4[4];
    const float2* Xr2[4];
#pragma unroll
    for (int j = 0; j < 4; ++j) {
        if (HIN) Xr2[j] = (const float2*)Xv + (size_t)r[j] * (K / 4);
        else     Xr4[j] = (const float4*)Xv + (size_t)r[j] * (K / 4);
    }

    float acc[4][4];
#pragma unroll
    for (int j = 0; j < 4; ++j)
#pragma unroll
        for (int c = 0; c < 4; ++c) acc[j][c] = 0.f;

#pragma unroll 4
    for (int kq = 0; kq < K / 4; ++kq) {
        float4 xv[4];
#pragma unroll
        for (int j = 0; j < 4; ++j)
            xv[j] = HIN ? h8_to_f4(Xr2[j][kq]) : Xr4[j][kq];
        float4 wv[4];
#pragma unroll
        for (int i = 0; i < 4; ++i)
            wv[i] = *(const float4*)(W + (size_t)(kq * 4 + i) * 64 + c0);
#pragma unroll
        for (int j = 0; j < 4; ++j) {
            acc[j][0] = fmaf(xv[j].x, wv[0].x, acc[j][0]);
            acc[j][1] = fmaf(xv[j].x, wv[0].y, acc[j][1]);
            acc[j][2] = fmaf(xv[j].x, wv[0].z, acc[j][2]);
            acc[j][3] = fmaf(xv[j].x, wv[0].w, acc[j][3]);
            acc[j][0] = fmaf(xv[j].y, wv[1].x, acc[j][0]);
            acc[j][1] = fmaf(xv[j].y, wv[1].y, acc[j][1]);
            acc[j][2] = fmaf(xv[j].y, wv[1].z, acc[j][2]);
            acc[j][3] = fmaf(xv[j].y, wv[1].w, acc[j][3]);
            acc[j][0] = fmaf(xv[j].z, wv[2].x, acc[j][0]);
            acc[j][1] = fmaf(xv[j].z, wv[2].y, acc[j][1]);
            acc[j][2] = fmaf(xv[j].z, wv[2].z, acc[j][2]);
            acc[j][3] = fmaf(xv[j].z, wv[2].w, acc[j][3]);
            acc[j][0] = fmaf(xv[j].w, wv[3].x, acc[j][0]);
            acc[j][1] = fmaf(xv[j].w, wv[3].y, acc[j][1]);
            acc[j][2] = fmaf(xv[j].w, wv[3].z, acc[j][2]);
            acc[j][3] = fmaf(xv[j].w, wv[3].w, acc[j][3]);
        }
    }

#pragma unroll
    for (int j = 0; j < 4; ++j) {
        int rr = n0 + r0 + j;
        if (rr < NN)
            Y[(size_t)rr * 16 + (t & 15)] =
                f4_to_h8(make_float4(acc[j][0], acc[j][1], acc[j][2], acc[j][3]));
    }
}

// ---- fp16 propagate core: 8 nodes/wave, lane-parallel edges + prefetch ----
// lane = slot*8 + fl; slot in [0,8), fl in [0,8). slotbase = lane & 56.
__device__ __forceinline__ void prop_gather8(const float4* __restrict__ X4,
                                             const int2* __restrict__ E,
                                             int e0, int e1, int fl, int slotbase,
                                             float acc[8], float acc2[8]) {
    if (e0 >= e1) return;
    int2 d = E[e0 + fl];                       // lane fl holds edge fl of batch
    for (int e = e0; e < e1; ) {
        int en = e + 8;
        int2 dn;
        if (en < e1) dn = E[en + fl];          // prefetch next batch
        int srcs[8]; float ws[8];
#pragma unroll
        for (int i = 0; i < 8; ++i) {
            srcs[i] = __shfl(d.x, slotbase + i, 64);
            ws[i] = __shfl(__int_as_float(d.y), slotbase + i, 64);
        }
        float4 rr[8];
#pragma unroll
        for (int i = 0; i < 8; ++i)
            rr[i] = X4[(size_t)srcs[i] * 8 + fl];
#pragma unroll
        for (int i = 0; i < 8; ++i) {
            f8 x = h16_to_f8(rr[i]);
            float* a = (i & 1) ? acc2 : acc;
#pragma unroll
            for (int j = 0; j < 8; ++j)
                a[j] = fmaf(ws[i], x.v[j], a[j]);
        }
        e = en;
        d = dn;
    }
}

// ---------------- propagate + bias + BN-stats (fp16 in, fp16 out) ----------
__global__ __launch_bounds__(256) void prop_stats_k(
        const float4* __restrict__ X4, const int* __restrict__ offs,
        const int2* __restrict__ edge2, const float* __restrict__ dinv,
        const float* __restrict__ bias, float4* __restrict__ Y4,
        float* __restrict__ stats) {
    const int lane = threadIdx.x & 63;
    const int wave = threadIdx.x >> 6;
    const int slot = lane >> 3;
    const int fl = lane & 7;
    const int slotbase = lane & 56;
    const int wid = blockIdx.x * 4 + wave;
    const int nw = gridDim.x * 4;

    float bias8[8];
    {
        float4 b0 = ((const float4*)bias)[fl * 2];
        float4 b1 = ((const float4*)bias)[fl * 2 + 1];
        bias8[0] = b0.x; bias8[1] = b0.y; bias8[2] = b0.z; bias8[3] = b0.w;
        bias8[4] = b1.x; bias8[5] = b1.y; bias8[6] = b1.z; bias8[7] = b1.w;
    }

    float s1[8], s2[8];
#pragma unroll
    for (int j = 0; j < 8; ++j) { s1[j] = 0.f; s2[j] = 0.f; }

    for (int g = wid; g < NGRP; g += nw) {
        int n = g * 8 + slot;
        float dn = dinv[n];
        float dd = dn * dn;
        f8 self = h16_to_f8(X4[(size_t)n * 8 + fl]);
        float acc[8], acc2[8];
#pragma unroll
        for (int j = 0; j < 8; ++j) { acc[j] = dd * self.v[j]; acc2[j] = 0.f; }
        int e0 = offs[n], e1 = offs[n + 1];
        prop_gather8(X4, edge2, e0, e1, fl, slotbase, acc, acc2);
        f8 o;
#pragma unroll
        for (int j = 0; j < 8; ++j) {
            float a = acc[j] + acc2[j] + bias8[j];
            o.v[j] = a;
            s1[j] += a;
            s2[j] = fmaf(a, a, s2[j]);
        }
        Y4[(size_t)n * 8 + fl] = f8_to_h16(o);
    }

    // reduce across the 8 slots (lanes differing in bits 3,4,5)
#pragma unroll
    for (int m = 8; m <= 32; m <<= 1) {
#pragma unroll
        for (int j = 0; j < 8; ++j) {
            s1[j] += __shfl_xor(s1[j], m, 64);
            s2[j] += __shfl_xor(s2[j], m, 64);
        }
    }

    __shared__ float red[4][8][16];
    if (lane < 8) {
#pragma unroll
        for (int j = 0; j < 8; ++j) {
            red[wave][lane][j] = s1[j];
            red[wave][lane][8 + j] = s2[j];
        }
    }
    __syncthreads();
    int t = threadIdx.x;
    if (t < 128) {
        int j = t & 63;            // feature index
        int isq = t >> 6;          // 0 = sum, 1 = sumsq
        int fli = j >> 3, c = (j & 7) + isq * 8;
        float a = red[0][fli][c] + red[1][fli][c] + red[2][fli][c] + red[3][fli][c];
        atomicAdd(&stats[isq * 64 + j], a);
    }
}

// ---------------- batchnorm + relu: fp16 in -> fp16 out ----------------
__global__ void bn_relu_k(const float4* __restrict__ Y4, const float* __restrict__ stats,
                          const float* __restrict__ g, const float* __restrict__ be,
                          float4* __restrict__ H4) {
    int i = blockIdx.x * blockDim.x + threadIdx.x;
    if (i >= NN * 8) return;
    int fg = i & 7;
    const float invN = 1.f / (float)NN;
    float4 sm0 = ((const float4*)stats)[fg * 2];
    float4 sm1 = ((const float4*)stats)[fg * 2 + 1];
    float4 sq0 = ((const float4*)(stats + 64))[fg * 2];
    float4 sq1 = ((const float4*)(stats + 64))[fg * 2 + 1];
    float4 gv0 = ((const float4*)g)[fg * 2];
    float4 gv1 = ((const float4*)g)[fg * 2 + 1];
    float4 bv0 = ((const float4*)be)[fg * 2];
    float4 bv1 = ((const float4*)be)[fg * 2 + 1];
    float sm[8] = { sm0.x, sm0.y, sm0.z, sm0.w, sm1.x, sm1.y, sm1.z, sm1.w };
    float sq[8] = { sq0.x, sq0.y, sq0.z, sq0.w, sq1.x, sq1.y, sq1.z, sq1.w };
    float gv[8] = { gv0.x, gv0.y, gv0.z, gv0.w, gv1.x, gv1.y, gv1.z, gv1.w };
    float bv[8] = { bv0.x, bv0.y, bv0.z, bv0.w, bv1.x, bv1.y, bv1.z, bv1.w };
    f8 y = h16_to_f8(Y4[i]);
    f8 o;
#pragma unroll
    for (int j = 0; j < 8; ++j) {
        float m = sm[j] * invN;
        float v = sq[j] * invN - m * m;
        float val = fmaf(gv[j] * rsqrtf(v + BN_EPS), y.v[j] - m, bv[j]);
        o.v[j] = val > 0.f ? val : 0.f;
    }
    H4[i] = f8_to_h16(o);
}

// ---------------- fp16 -> fp8 row conversion ----------------
__global__ void cvt16to8_k(const float4* __restrict__ H4, uint2* __restrict__ X8) {
    int i = blockIdx.x * blockDim.x + threadIdx.x;
    if (i >= NN * 8) return;
    f8 v = h16_to_f8(H4[i]);
    X8[i] = f_to_fp8x8(v.v);
}

// ---- fp8 APPNP: 16 nodes/wave, 16-row gathers, lane-parallel edges --------
// lane = slot*4 + fl; slot in [0,16), fl in [0,4) -> feats [fl*16, fl*16+16)
template <bool OUT16>
__global__ __launch_bounds__(256) void appnp8_k(
        const uint4* __restrict__ X8, const float4* __restrict__ H04,
        const int* __restrict__ offs, const int2* __restrict__ edge2,
        const float* __restrict__ dinv,
        uint4* __restrict__ Y8, float4* __restrict__ Y16) {
    const int lane = threadIdx.x & 63;
    const int wave = threadIdx.x >> 6;
    const int slot = lane >> 2;
    const int fl = lane & 3;
    const int quadbase = lane & 60;
    const int wid = blockIdx.x * 4 + wave;
    if (wid >= NG16) return;
    int n = wid * 16 + slot;
    float dn = dinv[n];
    float dd = dn * dn;
    float acc[16];
    {
        float self[16];
        fp8x16_to_f(X8[(size_t)n * 4 + fl], self);
#pragma unroll
        for (int j = 0; j < 16; ++j) acc[j] = dd * self[j];
    }
    int e0 = offs[n], e1 = offs[n + 1];
    if (e0 < e1) {
        int4 d = ((const int4*)(edge2 + e0))[fl];   // edges e0+2fl, e0+2fl+1
        for (int e = e0; e < e1; ) {
            int en = e + 8;
            int4 dn4;
            if (en < e1) dn4 = ((const int4*)(edge2 + en))[fl];
            int srcs[8]; float ws[8];
#pragma unroll
            for (int k = 0; k < 8; ++k) {
                int sl = quadbase + (k >> 1);
                srcs[k] = __shfl((k & 1) ? d.z : d.x, sl, 64);
                ws[k] = __shfl(__int_as_float((k & 1) ? d.w : d.y), sl, 64);
            }
            uint4 rr[8];
#pragma unroll
            for (int k = 0; k < 8; ++k)
                rr[k] = X8[(size_t)srcs[k] * 4 + fl];
#pragma unroll
            for (int k = 0; k < 8; ++k) {
                float x[16];
                fp8x16_to_f(rr[k], x);
#pragma unroll
                for (int j = 0; j < 16; ++j)
                    acc[j] = fmaf(ws[k], x[j], acc[j]);
            }
            e = en;
            d = dn4;
        }
    }
    // teleport: h0 fp16, feats [fl*16, fl*16+16) = float4 slots fl*2, fl*2+1
    f8 ha = h16_to_f8(H04[(size_t)n * 8 + fl * 2]);
    f8 hb = h16_to_f8(H04[(size_t)n * 8 + fl * 2 + 1]);
    float o[16];
#pragma unroll
    for (int j = 0; j < 8; ++j) {
        o[j] = fmaf(0.9f, acc[j], 0.1f * ha.v[j]);
        o[8 + j] = fmaf(0.9f, acc[8 + j], 0.1f * hb.v[j]);
    }
    if (OUT16) {
        f8 lo, hi;
#pragma unroll
        for (int j = 0; j < 8; ++j) { lo.v[j] = o[j]; hi.v[j] = o[8 + j]; }
        Y16[(size_t)n * 8 + fl * 2] = f8_to_h16(lo);
        Y16[(size_t)n * 8 + fl * 2 + 1] = f8_to_h16(hi);
    } else {
        Y8[(size_t)n * 4 + fl] = f_to_fp8x16(o);
    }
}

// ---------------- FC + log_softmax (fp16 in, fp32 out) ----------------
__global__ __launch_bounds__(256) void final_k(const float2* __restrict__ H2,
                                               const float* __restrict__ Wfc,
                                               const float* __restrict__ bfc,
                                               float* __restrict__ out) {
    const int t = threadIdx.x;
    const int n0 = blockIdx.x * 64;
    const int r0 = (t >> 4) << 2;
    const int c0 = (t & 15) << 2;

    int r[4];
#pragma unroll
    for (int j = 0; j < 4; ++j) {
        int rr = n0 + r0 + j;
        r[j] = rr < NN ? rr : NN - 1;
    }
    const float2* Xr[4];
#pragma unroll
    for (int j = 0; j < 4; ++j) Xr[j] = H2 + (size_t)r[j] * 16;

    float4 bf = *(const float4*)(bfc + c0);
    float acc[4][4];
#pragma unroll
    for (int j = 0; j < 4; ++j) {
        acc[j][0] = bf.x; acc[j][1] = bf.y; acc[j][2] = bf.z; acc[j][3] = bf.w;
    }

#pragma unroll 4
    for (int kq = 0; kq < 16; ++kq) {
        float4 xv[4];
#pragma unroll
        for (int j = 0; j < 4; ++j) xv[j] = h8_to_f4(Xr[j][kq]);
        float4 wv[4];
#pragma unroll
        for (int i = 0; i < 4; ++i)
            wv[i] = *(const float4*)(Wfc + (size_t)(kq * 4 + i) * 64 + c0);
#pragma unroll
        for (int j = 0; j < 4; ++j) {
            acc[j][0] = fmaf(xv[j].x, wv[0].x, acc[j][0]);
            acc[j][1] = fmaf(xv[j].x, wv[0].y, acc[j][1]);
            acc[j][2] = fmaf(xv[j].x, wv[0].z, acc[j][2]);
            acc[j][3] = fmaf(xv[j].x, wv[0].w, acc[j][3]);
            acc[j][0] = fmaf(xv[j].y, wv[1].x, acc[j][0]);
            acc[j][1] = fmaf(xv[j].y, wv[1].y, acc[j][1]);
            acc[j][2] = fmaf(xv[j].y, wv[1].z, acc[j][2]);
            acc[j][3] = fmaf(xv[j].y, wv[1].w, acc[j][3]);
            acc[j][0] = fmaf(xv[j].z, wv[2].x, acc[j][0]);
            acc[j][1] = fmaf(xv[j].z, wv[2].y, acc[j][1]);
            acc[j][2] = fmaf(xv[j].z, wv[2].z, acc[j][2]);
            acc[j][3] = fmaf(xv[j].z, wv[2].w, acc[j][3]);
            acc[j][0] = fmaf(xv[j].w, wv[3].x, acc[j][0]);
            acc[j][1] = fmaf(xv[j].w, wv[3].y, acc[j][1]);
            acc[j][2] = fmaf(xv[j].w, wv[3].z, acc[j][2]);
            acc[j][3] = fmaf(xv[j].w, wv[3].w, acc[j][3]);
        }
    }

#pragma unroll
    for (int j = 0; j < 4; ++j) {
        float m = fmaxf(fmaxf(acc[j][0], acc[j][1]), fmaxf(acc[j][2], acc[j][3]));
#pragma unroll
        for (int d = 1; d <= 8; d <<= 1) m = fmaxf(m, __shfl_xor(m, d, 64));
        float s = expf(acc[j][0] - m) + expf(acc[j][1] - m) +
                  expf(acc[j][2] - m) + expf(acc[j][3] - m);
#pragma unroll
        for (int d = 1; d <= 8; d <<= 1) s += __shfl_xor(s, d, 64);
        float lse = m + logf(s);
        int rr = n0 + r0 + j;
        if (rr < NN)
            *(float4*)(out + (size_t)rr * 64 + c0) =
                make_float4(acc[j][0] - lse, acc[j][1] - lse,
                            acc[j][2] - lse, acc[j][3] - lse);
    }
}

// ---------------- host launch ----------------

static inline char* alignup(char* p, size_t a) {
    return (char*)(((uintptr_t)p + a - 1) & ~(uintptr_t)(a - 1));
}

extern "C" void kernel_launch(void* const* d_in, const int* in_sizes, int n_in,
                              void* d_out, int out_size, void* d_ws, size_t ws_size,
                              hipStream_t stream) {
    const float* x   = (const float*)d_in[0];
    const int*   ei  = (const int*)d_in[1];
    const float* W1  = (const float*)d_in[2];
    const float* b1  = (const float*)d_in[3];
    const float* W2  = (const float*)d_in[4];
    const float* b2  = (const float*)d_in[5];
    const float* Wx  = (const float*)d_in[6];
    const float* bx  = (const float*)d_in[7];
    const float* g1  = (const float*)d_in[8];
    const float* be1 = (const float*)d_in[9];
    const float* g2  = (const float*)d_in[10];
    const float* be2 = (const float*)d_in[11];
    const float* g3  = (const float*)d_in[12];
    const float* be3 = (const float*)d_in[13];
    const float* Wfc = (const float*)d_in[14];
    const float* bfc = (const float*)d_in[15];
    float* out = (float*)d_out;

    const int* srcA = ei;
    const int* dstA = ei + NE;

    char* p = (char*)d_ws;
    int*   deg    = (int*)p;   p += NN * 4;
    int*   cursor = (int*)p;   p += NN * 4;
    float* stats  = (float*)p; p += 512 * 4;
    size_t zbytes = (size_t)(p - (char*)d_ws);
    p = alignup(p, 512);
    int*   offs  = (int*)p;    p += (NN + 4) * 4;   p = alignup(p, 512);
    float* dinv  = (float*)p;  p += NN * 4;         p = alignup(p, 512);
    int*   bsum  = (int*)p;    p += 256 * 4;
    int*   bpre  = (int*)p;    p += 256 * 4;        p = alignup(p, 512);
    int2*  edge2 = (int2*)p;   p += ((size_t)NE + 8 * NN + 256) * 8; p = alignup(p, 512);
    float4* tmpH = (float4*)p; p += (size_t)NN * 64 * 2; p = alignup(p, 512);
    float4* hbH  = (float4*)p; p += (size_t)NN * 64 * 2; p = alignup(p, 512);
    float4* apH  = (float4*)p; p += (size_t)NN * 64 * 2; p = alignup(p, 512);
    float4* pbH  = (float4*)p; p += (size_t)NN * 64 * 2; p = alignup(p, 512);
    uint4*  x8a  = (uint4*)p;  p += (size_t)NN * 64;     p = alignup(p, 512);
    uint4*  x8b  = (uint4*)p;  p += (size_t)NN * 64;

    hipMemsetAsync(d_ws, 0, zbytes, stream);

    count_k<<<(NE + 255) / 256, 256, 0, stream>>>(dstA, deg);
    dinv_k<<<(NN + 255) / 256, 256, 0, stream>>>(deg, dinv);
    scan1_k<<<SCAN_B, 256, 0, stream>>>(deg, offs, bsum);
    scan2_k<<<1, 256, 0, stream>>>(bsum, bpre, offs);
    scan3_k<<<(NN + 255) / 256, 256, 0, stream>>>(offs, bpre);
    pad_k<<<(NN + 255) / 256, 256, 0, stream>>>(deg, offs, edge2);
    scatter_k<<<(NE + 255) / 256, 256, 0, stream>>>(srcA, dstA, offs, cursor, dinv, edge2);

    const int MMG = (NN + 63) / 64;          // 782
    const int PG  = (NGRP + 3) / 4;          // 1563: one octet per wave
    const int AG  = (NG16 + 3) / 4;          // 782:  one 16-group per wave
    const int BNG = (NN * 8 + 255) / 256;    // 1563

    mm_k<INF_, false><<<MMG, 256, 0, stream>>>(x, W1, (float2*)tmpH);
    prop_stats_k<<<PG, 256, 0, stream>>>(tmpH, offs, edge2, dinv, b1, pbH, stats + 0 * 128);
    bn_relu_k<<<BNG, 256, 0, stream>>>(pbH, stats + 0 * 128, g1, be1, hbH);

    mm_k<HID, true><<<MMG, 256, 0, stream>>>(hbH, W2, (float2*)tmpH);
    prop_stats_k<<<PG, 256, 0, stream>>>(tmpH, offs, edge2, dinv, b2, pbH, stats + 1 * 128);
    bn_relu_k<<<BNG, 256, 0, stream>>>(pbH, stats + 1 * 128, g2, be2, hbH);

    for (int L = 0; L < 2; ++L) {
        mm_k<HID, true><<<MMG, 256, 0, stream>>>(hbH, Wx + (size_t)L * 64 * 64, (float2*)tmpH);
        prop_stats_k<<<PG, 256, 0, stream>>>(tmpH, offs, edge2, dinv, bx + (size_t)L * 64,
                                             pbH, stats + (2 + L) * 128);
        bn_relu_k<<<BNG, 256, 0, stream>>>(pbH, stats + (2 + L) * 128, g3, be3, hbH);
    }

    // APPNP in fp8: x8a <- fp8(hbH); 9 fp8->fp8 iters ping-pong; 10th -> fp16 apH
    cvt16to8_k<<<BNG, 256, 0, stream>>>(hbH, (uint2*)x8a);
    const uint4* cur8 = x8a;
    for (int it = 0; it < 9; ++it) {
        uint4* o8 = (cur8 == x8a) ? x8b : x8a;
        appnp8_k<false><<<AG, 256, 0, stream>>>(cur8, hbH, offs, edge2, dinv, o8, nullptr);
        cur8 = o8;
    }
    appnp8_k<true><<<AG, 256, 0, stream>>>(cur8, hbH, offs, edge2, dinv, nullptr, apH);

    final_k<<<MMG, 256, 0, stream>>>((const float2*)apH, Wfc, bfc, out);
}